// Round 4
// baseline (410.307 us; speedup 1.0000x reference)
//
#include <hip/hip_runtime.h>
#include <hip/hip_bf16.h>
#include <stdint.h>

#define HID  128
#define N1   512
#define NCAT 1024

typedef _Float16 f16;
typedef __attribute__((ext_vector_type(8))) _Float16 f16x8;
typedef __attribute__((ext_vector_type(4))) _Float16 f16x4;
typedef __attribute__((ext_vector_type(2))) _Float16 f16x2;
typedef __attribute__((ext_vector_type(8))) short   short8;
typedef __attribute__((ext_vector_type(4))) float   floatx4;
typedef __attribute__((ext_vector_type(2))) float   floatx2;

static __device__ __forceinline__ short f2bf(float x) {
  uint32_t u = __builtin_bit_cast(uint32_t, x);
  uint32_t r = (u + 0x7FFFu + ((u >> 16) & 1u)) >> 16;
  return (short)r;
}
static __device__ __forceinline__ float bf2f(short s) {
  uint32_t u = ((uint32_t)(uint16_t)s) << 16;
  return __builtin_bit_cast(float, u);
}

// pack two f32 -> f16x2 (v_cvt_pkrtz_f16_f32), with type fix
static __device__ __forceinline__ f16x2 pkrtz(float a, float b) {
  return __builtin_bit_cast(f16x2, __builtin_amdgcn_cvt_pkrtz(a, b));
}

// ---------------- tier-1 (fp16) pipeline ----------------

// BT[n][k] = f16( (n<512) ? W1[k][n] : W1[k+128][n-512] )
__global__ __launch_bounds__(256) void conv_bt16(
    const float* __restrict__ W1, f16* __restrict__ BT) {
  int idx = blockIdx.x * 256 + threadIdx.x;  // 131072
  int n = idx >> 7;
  int k = idx & 127;
  float w = (n < N1) ? W1[k * N1 + n] : W1[(k + HID) * N1 + (n - N1)];
  BT[idx] = (f16)w;
}

// W2T[c][j] = f16(W2[j][c]), c in {0,1}, j in [0,512)
__global__ __launch_bounds__(256) void conv_w2t(
    const float* __restrict__ W2, f16* __restrict__ W2T) {
  int idx = blockIdx.x * 256 + threadIdx.x;  // 1024
  int c = idx >> 9;
  int j = idx & 511;
  W2T[idx] = (f16)W2[j * 2 + c];
}

// A'[m][k] = f16(relu(feats[m][k]))
__global__ __launch_bounds__(256) void prep_a16(
    const float* __restrict__ feats, f16* __restrict__ A, int total4) {
  int idx = blockIdx.x * 256 + threadIdx.x;
  if (idx >= total4) return;
  floatx4 f = *(const floatx4*)(feats + (size_t)idx * 4);
  f16x4 o;
#pragma unroll
  for (int j = 0; j < 4; ++j) {
    float x = f[j]; x = x > 0.f ? x : 0.f;
    o[j] = (f16)x;
  }
  *(f16x4*)(A + (size_t)idx * 4) = o;
}

// GH[m][n] = sum_k A'[m][k]*BT[n][k]  (+ b1[n] for n<512), f16 out.
// Operand-swapped MFMA: D = mfma(bfr, afr) gives D[col-of-W1][node-row]:
//   lane&15 -> node row, quad*4+r -> W1 col  => per lane 4 CONSECUTIVE cols
//   of one node row -> one packed 8B store. No LDS, no transpose.
// Wave = 32 rows x 64 cols; block = 4 waves = 128 rows x 64 cols.
// grid = (16 col-groups fast, ceil(n/128)) for A-window sharing in L2/L3.
__global__ __launch_bounds__(256) void gemm3_kernel(
    const f16* __restrict__ A,      // (n_nodes,128)
    const f16* __restrict__ BT,     // (1024,128)
    const float* __restrict__ b1,   // (512,)
    f16* __restrict__ GH,           // (n_nodes,1024)
    int n_nodes) {
  const int wave = threadIdx.x >> 6;
  const int lane = threadIdx.x & 63;
  const int quad = lane >> 4;
  const int l16  = lane & 15;
  const int c0 = blockIdx.x * 64;
  const int r0 = blockIdx.y * 128 + wave * 32;
  const bool hasB = (c0 < N1);

  // B fragments (W1 cols as MFMA "A" operand): BT[(c0+nn*16+l16)][quad*8 + kk*32 + j]
  f16x8 bfr[4][4];
#pragma unroll
  for (int nn = 0; nn < 4; ++nn) {
    const f16* brow = BT + (((size_t)(c0 + nn * 16 + l16)) << 7) + quad * 8;
#pragma unroll
    for (int kk = 0; kk < 4; ++kk)
      bfr[nn][kk] = *(const f16x8*)(brow + kk * 32);
  }

#pragma unroll
  for (int mt = 0; mt < 2; ++mt) {
    const int rbase = r0 + mt * 16;
    int m = rbase + l16;
    const bool ok = (m < n_nodes);
    if (m >= n_nodes) m = n_nodes - 1;
    const f16* arow = A + (((size_t)m) << 7) + quad * 8;
    f16x8 afr[4];
#pragma unroll
    for (int kk = 0; kk < 4; ++kk)
      afr[kk] = *(const f16x8*)(arow + kk * 32);

    floatx4 acc[4];
#pragma unroll
    for (int nn = 0; nn < 4; ++nn) acc[nn] = (floatx4){0.f, 0.f, 0.f, 0.f};
#pragma unroll
    for (int kk = 0; kk < 4; ++kk)
#pragma unroll
      for (int nn = 0; nn < 4; ++nn)
        acc[nn] = __builtin_amdgcn_mfma_f32_16x16x32_f16(bfr[nn][kk], afr[kk], acc[nn], 0, 0, 0);

    // store: row = rbase + l16 ; cols = c0 + nn*16 + quad*4 + {0..3}
    const size_t rowoff = (size_t)(rbase + l16) * NCAT;
#pragma unroll
    for (int nn = 0; nn < 4; ++nn) {
      const int colbase = c0 + nn * 16 + quad * 4;
      floatx4 bb = (floatx4){0.f, 0.f, 0.f, 0.f};
      if (hasB) bb = *(const floatx4*)(b1 + colbase);
      f16x2 lo = pkrtz(acc[nn][0] + bb[0], acc[nn][1] + bb[1]);
      f16x2 hi = pkrtz(acc[nn][2] + bb[2], acc[nn][3] + bb[3]);
      f16x4 o = {lo[0], lo[1], hi[0], hi[1]};
      if (ok) *(f16x4*)(GH + rowoff + colbase) = o;
    }
  }
}

// Edge phase: out[e] = relu(G'[u] + H[v]) @ W2T + b2  (b1 already folded into G').
// 16 lanes per edge, 4 edges per wave. Lane t covers j = q*128 + t*8 + i.
// Packed f16 math: v_pk_add_f16 / v_pk_max_f16 / v_dot2_f32_f16.
__global__ __launch_bounds__(256) void edge5_kernel(
    const f16* __restrict__ GH, const int* __restrict__ edges,
    const f16* __restrict__ W2T, const float* __restrict__ b2,
    float* __restrict__ out, int n_edges) {
  const int wave = threadIdx.x >> 6;
  const int lane = threadIdx.x & 63;
  const int sub  = lane >> 4;   // edge within wave
  const int t    = lane & 15;   // lane within edge
  const int e = (blockIdx.x * 4 + wave) * 4 + sub;
  const bool valid = (e < n_edges);
  const int ec = valid ? e : (n_edges - 1);

  const int u = edges[ec];
  const int v = edges[n_edges + ec];
  const f16* gp = GH + (size_t)u * NCAT + t * 8;
  const f16* hp = GH + (size_t)v * NCAT + N1 + t * 8;

  f16x8 g[4], h[4];
#pragma unroll
  for (int q = 0; q < 4; ++q) {
    g[q] = *(const f16x8*)(gp + q * 128);
    h[q] = *(const f16x8*)(hp + q * 128);
  }
  f16x8 w0[4], w1[4];
#pragma unroll
  for (int q = 0; q < 4; ++q) {
    w0[q] = *(const f16x8*)(W2T + q * 128 + t * 8);
    w1[q] = *(const f16x8*)(W2T + N1 + q * 128 + t * 8);
  }

  const f16x8 zero8 = {0, 0, 0, 0, 0, 0, 0, 0};
  float s0 = 0.f, s1 = 0.f;
#pragma unroll
  for (int q = 0; q < 4; ++q) {
    f16x8 z = g[q] + h[q];                       // v_pk_add_f16 x4
    z = __builtin_elementwise_max(z, zero8);     // v_pk_max_f16 x4
#pragma unroll
    for (int i = 0; i < 4; ++i) {
      f16x2 zp = {z[2 * i], z[2 * i + 1]};
      f16x2 wp0 = {w0[q][2 * i], w0[q][2 * i + 1]};
      f16x2 wp1 = {w1[q][2 * i], w1[q][2 * i + 1]};
#if __has_builtin(__builtin_amdgcn_fdot2)
      s0 = __builtin_amdgcn_fdot2(__builtin_bit_cast(__fp16 __attribute__((ext_vector_type(2))), zp),
                                  __builtin_bit_cast(__fp16 __attribute__((ext_vector_type(2))), wp0),
                                  s0, false);
      s1 = __builtin_amdgcn_fdot2(__builtin_bit_cast(__fp16 __attribute__((ext_vector_type(2))), zp),
                                  __builtin_bit_cast(__fp16 __attribute__((ext_vector_type(2))), wp1),
                                  s1, false);
#else
      s0 += (float)zp[0] * (float)wp0[0] + (float)zp[1] * (float)wp0[1];
      s1 += (float)zp[0] * (float)wp1[0] + (float)zp[1] * (float)wp1[1];
#endif
    }
  }
#pragma unroll
  for (int off = 8; off > 0; off >>= 1) {
    s0 += __shfl_down(s0, off, 16);
    s1 += __shfl_down(s1, off, 16);
  }
  if (t == 0 && valid) {
    floatx2 o = {s0 + b2[0], s1 + b2[1]};
    *(floatx2*)(out + 2 * (size_t)e) = o;
  }
}

// ---------------- tier-2 fallback (bf16, R1-proven) ----------------

__global__ __launch_bounds__(256) void conv_bt_bf(
    const float* __restrict__ W1, short* __restrict__ BT) {
  int idx = blockIdx.x * 256 + threadIdx.x;
  int n = idx >> 7;
  int k = idx & 127;
  float w = (n < N1) ? W1[k * N1 + n] : W1[(k + HID) * N1 + (n - N1)];
  BT[idx] = f2bf(w);
}

typedef __attribute__((ext_vector_type(8))) __bf16 bf16x8;

__global__ __launch_bounds__(256) void gemm_bf(
    const float* __restrict__ feats, const short* __restrict__ BT,
    short* __restrict__ GH, int n_nodes) {
  const int wave = threadIdx.x >> 6;
  const int lane = threadIdx.x & 63;
  const int quad = lane >> 4;
  const int l16  = lane & 15;
  const int row0 = blockIdx.x * 64 + wave * 16;
  const int n0   = blockIdx.y * 128;
  const int m  = row0 + l16;
  const int mc = (m < n_nodes) ? m : (n_nodes - 1);
  const float* arow = feats + (size_t)mc * HID;
  floatx4 acc[8];
#pragma unroll
  for (int i = 0; i < 8; ++i) acc[i] = (floatx4){0.f, 0.f, 0.f, 0.f};
#pragma unroll
  for (int kk = 0; kk < 4; ++kk) {
    const int kbase = kk * 32 + quad * 8;
    floatx4 a0 = *(const floatx4*)(arow + kbase);
    floatx4 a1 = *(const floatx4*)(arow + kbase + 4);
    short8 af;
#pragma unroll
    for (int j = 0; j < 4; ++j) { float x = a0[j]; af[j] = f2bf(x > 0.f ? x : 0.f); }
#pragma unroll
    for (int j = 0; j < 4; ++j) { float x = a1[j]; af[4 + j] = f2bf(x > 0.f ? x : 0.f); }
    bf16x8 afrag = __builtin_bit_cast(bf16x8, af);
#pragma unroll
    for (int nn = 0; nn < 8; ++nn) {
      const int n = n0 + nn * 16 + l16;
      short8 bs = *(const short8*)(BT + (size_t)n * HID + kbase);
      acc[nn] = __builtin_amdgcn_mfma_f32_16x16x32_bf16(
          afrag, __builtin_bit_cast(bf16x8, bs), acc[nn], 0, 0, 0);
    }
  }
#pragma unroll
  for (int nn = 0; nn < 8; ++nn) {
    const int col = n0 + nn * 16 + l16;
#pragma unroll
    for (int r = 0; r < 4; ++r) {
      const int row = row0 + quad * 4 + r;
      if (row < n_nodes) GH[(size_t)row * NCAT + col] = f2bf(acc[nn][r]);
    }
  }
}

__global__ __launch_bounds__(256) void edge2_bf(
    const short* __restrict__ GH, const int* __restrict__ edges,
    const float* __restrict__ b1, const float* __restrict__ W2,
    const float* __restrict__ b2, float* __restrict__ out, int n_edges) {
  const int wave = threadIdx.x >> 6;
  const int lane = threadIdx.x & 63;
  const int w = blockIdx.x * 4 + wave;
  const int e0 = 2 * w;
  if (e0 >= n_edges) return;
  const bool has1 = (e0 + 1 < n_edges);
  const int j0 = lane * 8;
  const int u0 = edges[e0];
  const int v0 = edges[n_edges + e0];
  const int u1 = has1 ? edges[e0 + 1] : u0;
  const int v1 = has1 ? edges[n_edges + e0 + 1] : v0;
  short8 g0 = *(const short8*)(GH + (size_t)u0 * NCAT + j0);
  short8 h0 = *(const short8*)(GH + (size_t)v0 * NCAT + N1 + j0);
  short8 g1 = *(const short8*)(GH + (size_t)u1 * NCAT + j0);
  short8 h1 = *(const short8*)(GH + (size_t)v1 * NCAT + N1 + j0);
  float bv[8];
  {
    floatx4 t0 = *(const floatx4*)(b1 + j0);
    floatx4 t1 = *(const floatx4*)(b1 + j0 + 4);
#pragma unroll
    for (int j = 0; j < 4; ++j) { bv[j] = t0[j]; bv[4 + j] = t1[j]; }
  }
  float wv[16];
#pragma unroll
  for (int q = 0; q < 4; ++q) {
    floatx4 tt = *(const floatx4*)(W2 + (size_t)j0 * 2 + q * 4);
#pragma unroll
    for (int j = 0; j < 4; ++j) wv[q * 4 + j] = tt[j];
  }
  float s00 = 0.f, s01 = 0.f, s10 = 0.f, s11 = 0.f;
#pragma unroll
  for (int j = 0; j < 8; ++j) {
    float p0 = bf2f(g0[j]) + bf2f(h0[j]) + bv[j];
    p0 = p0 > 0.f ? p0 : 0.f;
    s00 += p0 * wv[2 * j];
    s01 += p0 * wv[2 * j + 1];
    float p1 = bf2f(g1[j]) + bf2f(h1[j]) + bv[j];
    p1 = p1 > 0.f ? p1 : 0.f;
    s10 += p1 * wv[2 * j];
    s11 += p1 * wv[2 * j + 1];
  }
#pragma unroll
  for (int off = 32; off > 0; off >>= 1) {
    s00 += __shfl_down(s00, off, 64);
    s01 += __shfl_down(s01, off, 64);
    s10 += __shfl_down(s10, off, 64);
    s11 += __shfl_down(s11, off, 64);
  }
  if (lane == 0) {
    out[2 * (size_t)e0]     = s00 + b2[0];
    out[2 * (size_t)e0 + 1] = s01 + b2[1];
    if (has1) {
      out[2 * (size_t)e0 + 2] = s10 + b2[0];
      out[2 * (size_t)e0 + 3] = s11 + b2[1];
    }
  }
}

// ---------------- tier-3 fallback: direct fp32 ----------------
__global__ __launch_bounds__(256) void slow_kernel(
    const float* __restrict__ feats, const int* __restrict__ edges,
    const float* __restrict__ W1, const float* __restrict__ b1,
    const float* __restrict__ W2, const float* __restrict__ b2,
    float* __restrict__ out, int n_edges) {
  const int wave = threadIdx.x >> 6;
  const int lane = threadIdx.x & 63;
  const int edge = blockIdx.x * 4 + wave;
  if (edge >= n_edges) return;
  const int u = edges[edge];
  const int v = edges[n_edges + edge];
  float f[4];
  f[0] = feats[(size_t)u * HID + lane];
  f[1] = feats[(size_t)u * HID + 64 + lane];
  f[2] = feats[(size_t)v * HID + lane];
  f[3] = feats[(size_t)v * HID + 64 + lane];
#pragma unroll
  for (int i = 0; i < 4; ++i) f[i] = f[i] > 0.f ? f[i] : 0.f;
  const int j0 = lane * 8;
  float acc[8];
#pragma unroll
  for (int j = 0; j < 8; ++j) acc[j] = 0.f;
#pragma unroll
  for (int seg = 0; seg < 4; ++seg) {
    float fs = f[seg];
    for (int k2 = 0; k2 < 64; ++k2) {
      float fk = __shfl(fs, k2, 64);
      const float* wr = W1 + (size_t)(seg * 64 + k2) * N1 + j0;
#pragma unroll
      for (int j = 0; j < 8; ++j) acc[j] += fk * wr[j];
    }
  }
  float s0 = 0.f, s1 = 0.f;
#pragma unroll
  for (int j = 0; j < 8; ++j) {
    float p = acc[j] + b1[j0 + j];
    p = p > 0.f ? p : 0.f;
    s0 += p * W2[(size_t)(j0 + j) * 2];
    s1 += p * W2[(size_t)(j0 + j) * 2 + 1];
  }
#pragma unroll
  for (int off = 32; off > 0; off >>= 1) {
    s0 += __shfl_down(s0, off, 64);
    s1 += __shfl_down(s1, off, 64);
  }
  if (lane == 0) {
    out[2 * (size_t)edge]     = s0 + b2[0];
    out[2 * (size_t)edge + 1] = s1 + b2[1];
  }
}

extern "C" void kernel_launch(void* const* d_in, const int* in_sizes, int n_in,
                              void* d_out, int out_size, void* d_ws, size_t ws_size,
                              hipStream_t stream) {
  const float* feats = (const float*)d_in[0];
  const int*   edges = (const int*)d_in[1];
  const float* W1    = (const float*)d_in[2];
  const float* b1    = (const float*)d_in[3];
  const float* W2    = (const float*)d_in[4];
  const float* b2    = (const float*)d_in[5];
  float* out = (float*)d_out;

  const int n_nodes = in_sizes[0] / HID;
  const int n_edges = in_sizes[1] / 2;

  const size_t bt_bytes  = (size_t)NCAT * HID * 2;        // 256 KiB
  const size_t w2t_bytes = 4096;                          // 2 KiB used
  const size_t a_bytes   = (size_t)n_nodes * HID * 2;     // ~25.6 MB
  const size_t gh_bytes  = (size_t)n_nodes * NCAT * 2;    // ~204.8 MB

  if (ws_size >= bt_bytes + w2t_bytes + a_bytes + gh_bytes) {
    f16* BT  = (f16*)d_ws;
    f16* W2T = (f16*)((char*)d_ws + bt_bytes);
    f16* A   = (f16*)((char*)d_ws + bt_bytes + w2t_bytes);
    f16* GH  = (f16*)((char*)d_ws + bt_bytes + w2t_bytes + a_bytes);
    conv_bt16<<<(NCAT * HID) / 256, 256, 0, stream>>>(W1, BT);
    conv_w2t<<<4, 256, 0, stream>>>(W2, W2T);
    const int total4 = n_nodes * HID / 4;
    prep_a16<<<(total4 + 255) / 256, 256, 0, stream>>>(feats, A, total4);
    dim3 grid(NCAT / 64, (n_nodes + 127) / 128);
    gemm3_kernel<<<grid, 256, 0, stream>>>(A, BT, b1, GH, n_nodes);
    const int nwaves = (n_edges + 3) / 4;
    edge5_kernel<<<(nwaves + 3) / 4, 256, 0, stream>>>(GH, edges, W2T, b2, out, n_edges);
  } else if (ws_size >= bt_bytes + gh_bytes) {
    short* BT = (short*)d_ws;
    short* GH = (short*)((char*)d_ws + bt_bytes);
    conv_bt_bf<<<(NCAT * HID) / 256, 256, 0, stream>>>(W1, BT);
    dim3 grid((n_nodes + 63) / 64, NCAT / 128);
    gemm_bf<<<grid, 256, 0, stream>>>(feats, BT, GH, n_nodes);
    edge2_bf<<<((n_edges + 1) / 2 + 3) / 4, 256, 0, stream>>>(GH, edges, b1, W2, b2, out, n_edges);
  } else {
    slow_kernel<<<(n_edges + 3) / 4, 256, 0, stream>>>(feats, edges, W1, b1, W2, b2, out, n_edges);
  }
}

// Round 5
// 340.686 us; speedup vs baseline: 1.2044x; 1.2044x over previous
//
#include <hip/hip_runtime.h>
#include <hip/hip_bf16.h>
#include <stdint.h>

#define HID  128
#define N1   512
#define NCAT 1024

typedef _Float16 f16;
typedef __attribute__((ext_vector_type(8))) _Float16 f16x8;
typedef __attribute__((ext_vector_type(4))) _Float16 f16x4;
typedef __attribute__((ext_vector_type(2))) _Float16 f16x2;
typedef __attribute__((ext_vector_type(8))) short   short8;
typedef __attribute__((ext_vector_type(4))) float   floatx4;
typedef __attribute__((ext_vector_type(2))) float   floatx2;

static __device__ __forceinline__ short f2bf(float x) {
  uint32_t u = __builtin_bit_cast(uint32_t, x);
  uint32_t r = (u + 0x7FFFu + ((u >> 16) & 1u)) >> 16;
  return (short)r;
}
static __device__ __forceinline__ float bf2f(short s) {
  uint32_t u = ((uint32_t)(uint16_t)s) << 16;
  return __builtin_bit_cast(float, u);
}
static __device__ __forceinline__ f16x2 pkrtz(float a, float b) {
  return __builtin_bit_cast(f16x2, __builtin_amdgcn_cvt_pkrtz(a, b));
}

// ---------------- tier-1 (fp16) pipeline ----------------

// BT[n][k] = f16( (n<512) ? W1[k][n] : W1[k+128][n-512] )
__global__ __launch_bounds__(256) void conv_bt16(
    const float* __restrict__ W1, f16* __restrict__ BT) {
  int idx = blockIdx.x * 256 + threadIdx.x;  // 131072
  int n = idx >> 7;
  int k = idx & 127;
  float w = (n < N1) ? W1[k * N1 + n] : W1[(k + HID) * N1 + (n - N1)];
  BT[idx] = (f16)w;
}

// idx<1024: W2T[c][j] = f16(W2[j][c]);  idx in [1024,1536): B1h[j] = f16(b1[j])
__global__ __launch_bounds__(256) void conv_misc(
    const float* __restrict__ W2, const float* __restrict__ b1,
    f16* __restrict__ W2T, f16* __restrict__ B1h) {
  int idx = blockIdx.x * 256 + threadIdx.x;  // 1536
  if (idx < 1024) {
    int c = idx >> 9;
    int j = idx & 511;
    W2T[idx] = (f16)W2[j * 2 + c];
  } else {
    int j = idx - 1024;
    B1h[j] = (f16)b1[j];
  }
}

// A'[m][k] = f16(relu(feats[m][k]))
__global__ __launch_bounds__(256) void prep_a16(
    const float* __restrict__ feats, f16* __restrict__ A, int total4) {
  int idx = blockIdx.x * 256 + threadIdx.x;
  if (idx >= total4) return;
  floatx4 f = *(const floatx4*)(feats + (size_t)idx * 4);
  f16x4 o;
#pragma unroll
  for (int j = 0; j < 4; ++j) {
    float x = f[j]; x = x > 0.f ? x : 0.f;
    o[j] = (f16)x;
  }
  *(f16x4*)(A + (size_t)idx * 4) = o;
}

// GH[m][n] = sum_k A'[m][k]*BT[n][k]  (+ b1[n] for n<512), f16 out.
// Operand-swapped MFMA (D = mfma(bfr, afr)): lane&15 -> node row,
// quad*4+r -> W1 col => per lane 4 consecutive cols -> packed 8B store.
// Wave = 128 rows x 64 cols (8 m-tiles, amortizes B-frag load 4x vs gemm3),
// 1-deep A prefetch. Block = 4 waves = 512 rows x 64 cols.
// grid = (16 col-groups fast, ceil(n/512)) for A-window sharing in L2.
__global__ __launch_bounds__(256) void gemm4_kernel(
    const f16* __restrict__ A,      // (n_nodes,128)
    const f16* __restrict__ BT,     // (1024,128)
    const f16* __restrict__ B1h,    // (512,)
    f16* __restrict__ GH,           // (n_nodes,1024)
    int n_nodes) {
  const int wave = threadIdx.x >> 6;
  const int lane = threadIdx.x & 63;
  const int quad = lane >> 4;
  const int l16  = lane & 15;
  const int c0 = blockIdx.x * 64;
  const int r0 = blockIdx.y * 512 + wave * 128;
  const bool hasB = (c0 < N1);

  // B fragments: BT[(c0+nn*16+l16)][quad*8 + kk*32 + j]  (64 VGPRs, persistent)
  f16x8 bfr[4][4];
#pragma unroll
  for (int nn = 0; nn < 4; ++nn) {
    const f16* brow = BT + (((size_t)(c0 + nn * 16 + l16)) << 7) + quad * 8;
#pragma unroll
    for (int kk = 0; kk < 4; ++kk)
      bfr[nn][kk] = *(const f16x8*)(brow + kk * 32);
  }

  // bias (f16, 8B per lane-group)
  f16x4 bb[4];
#pragma unroll
  for (int nn = 0; nn < 4; ++nn) {
    const int colbase = (c0 + nn * 16 + quad * 4) & (N1 - 1);
    bb[nn] = *(const f16x4*)(B1h + colbase);
  }

  // prefetch A for mt=0
  f16x8 anext[4];
  {
    int m = r0 + l16;
    if (m >= n_nodes) m = n_nodes - 1;
    const f16* arow = A + (((size_t)m) << 7) + quad * 8;
#pragma unroll
    for (int kk = 0; kk < 4; ++kk) anext[kk] = *(const f16x8*)(arow + kk * 32);
  }

#pragma unroll
  for (int mt = 0; mt < 8; ++mt) {
    f16x8 afr[4];
#pragma unroll
    for (int kk = 0; kk < 4; ++kk) afr[kk] = anext[kk];

    if (mt < 7) {  // prefetch next tile
      int m = r0 + (mt + 1) * 16 + l16;
      if (m >= n_nodes) m = n_nodes - 1;
      const f16* arow = A + (((size_t)m) << 7) + quad * 8;
#pragma unroll
      for (int kk = 0; kk < 4; ++kk) anext[kk] = *(const f16x8*)(arow + kk * 32);
    }

    floatx4 acc[4];
#pragma unroll
    for (int nn = 0; nn < 4; ++nn) acc[nn] = (floatx4){0.f, 0.f, 0.f, 0.f};
#pragma unroll
    for (int kk = 0; kk < 4; ++kk)
#pragma unroll
      for (int nn = 0; nn < 4; ++nn)
        acc[nn] = __builtin_amdgcn_mfma_f32_16x16x32_f16(bfr[nn][kk], afr[kk], acc[nn], 0, 0, 0);

    const int rbase = r0 + mt * 16;
    const bool ok = (rbase + l16 < n_nodes);
    const size_t rowoff = (size_t)(rbase + l16) * NCAT;
#pragma unroll
    for (int nn = 0; nn < 4; ++nn) {
      const int colbase = c0 + nn * 16 + quad * 4;
      f16x2 lo = pkrtz(acc[nn][0], acc[nn][1]);
      f16x2 hi = pkrtz(acc[nn][2], acc[nn][3]);
      f16x4 o = {lo[0], lo[1], hi[0], hi[1]};
      if (hasB) o = o + bb[nn];   // 2x v_pk_add_f16
      if (ok) *(f16x4*)(GH + rowoff + colbase) = o;
    }
  }
}

// Edge phase: out[e] = relu(G'[u] + H[v]) @ W2T + b2  (b1 folded into G').
// 16 lanes per edge, 4 edges per wave.
__global__ __launch_bounds__(256) void edge5_kernel(
    const f16* __restrict__ GH, const int* __restrict__ edges,
    const f16* __restrict__ W2T, const float* __restrict__ b2,
    float* __restrict__ out, int n_edges) {
  const int wave = threadIdx.x >> 6;
  const int lane = threadIdx.x & 63;
  const int sub  = lane >> 4;
  const int t    = lane & 15;
  const int e = (blockIdx.x * 4 + wave) * 4 + sub;
  const bool valid = (e < n_edges);
  const int ec = valid ? e : (n_edges - 1);

  const int u = edges[ec];
  const int v = edges[n_edges + ec];
  const f16* gp = GH + (size_t)u * NCAT + t * 8;
  const f16* hp = GH + (size_t)v * NCAT + N1 + t * 8;

  f16x8 g[4], h[4];
#pragma unroll
  for (int q = 0; q < 4; ++q) {
    g[q] = *(const f16x8*)(gp + q * 128);
    h[q] = *(const f16x8*)(hp + q * 128);
  }
  f16x8 w0[4], w1[4];
#pragma unroll
  for (int q = 0; q < 4; ++q) {
    w0[q] = *(const f16x8*)(W2T + q * 128 + t * 8);
    w1[q] = *(const f16x8*)(W2T + N1 + q * 128 + t * 8);
  }

  const f16x8 zero8 = {0, 0, 0, 0, 0, 0, 0, 0};
  float s0 = 0.f, s1 = 0.f;
#pragma unroll
  for (int q = 0; q < 4; ++q) {
    f16x8 z = g[q] + h[q];
    z = __builtin_elementwise_max(z, zero8);
#pragma unroll
    for (int i = 0; i < 4; ++i) {
      f16x2 zp = {z[2 * i], z[2 * i + 1]};
      f16x2 wp0 = {w0[q][2 * i], w0[q][2 * i + 1]};
      f16x2 wp1 = {w1[q][2 * i], w1[q][2 * i + 1]};
#if __has_builtin(__builtin_amdgcn_fdot2)
      s0 = __builtin_amdgcn_fdot2(__builtin_bit_cast(__fp16 __attribute__((ext_vector_type(2))), zp),
                                  __builtin_bit_cast(__fp16 __attribute__((ext_vector_type(2))), wp0),
                                  s0, false);
      s1 = __builtin_amdgcn_fdot2(__builtin_bit_cast(__fp16 __attribute__((ext_vector_type(2))), zp),
                                  __builtin_bit_cast(__fp16 __attribute__((ext_vector_type(2))), wp1),
                                  s1, false);
#else
      s0 += (float)zp[0] * (float)wp0[0] + (float)zp[1] * (float)wp0[1];
      s1 += (float)zp[0] * (float)wp1[0] + (float)zp[1] * (float)wp1[1];
#endif
    }
  }
#pragma unroll
  for (int off = 8; off > 0; off >>= 1) {
    s0 += __shfl_down(s0, off, 16);
    s1 += __shfl_down(s1, off, 16);
  }
  if (t == 0 && valid) {
    floatx2 o = {s0 + b2[0], s1 + b2[1]};
    *(floatx2*)(out + 2 * (size_t)e) = o;
  }
}

// ---------------- tier-2 fallback (bf16) ----------------

__global__ __launch_bounds__(256) void conv_bt_bf(
    const float* __restrict__ W1, short* __restrict__ BT) {
  int idx = blockIdx.x * 256 + threadIdx.x;
  int n = idx >> 7;
  int k = idx & 127;
  float w = (n < N1) ? W1[k * N1 + n] : W1[(k + HID) * N1 + (n - N1)];
  BT[idx] = f2bf(w);
}

typedef __attribute__((ext_vector_type(8))) __bf16 bf16x8;

__global__ __launch_bounds__(256) void gemm_bf(
    const float* __restrict__ feats, const short* __restrict__ BT,
    short* __restrict__ GH, int n_nodes) {
  const int wave = threadIdx.x >> 6;
  const int lane = threadIdx.x & 63;
  const int quad = lane >> 4;
  const int l16  = lane & 15;
  const int row0 = blockIdx.x * 64 + wave * 16;
  const int n0   = blockIdx.y * 128;
  const int m  = row0 + l16;
  const int mc = (m < n_nodes) ? m : (n_nodes - 1);
  const float* arow = feats + (size_t)mc * HID;
  floatx4 acc[8];
#pragma unroll
  for (int i = 0; i < 8; ++i) acc[i] = (floatx4){0.f, 0.f, 0.f, 0.f};
#pragma unroll
  for (int kk = 0; kk < 4; ++kk) {
    const int kbase = kk * 32 + quad * 8;
    floatx4 a0 = *(const floatx4*)(arow + kbase);
    floatx4 a1 = *(const floatx4*)(arow + kbase + 4);
    short8 af;
#pragma unroll
    for (int j = 0; j < 4; ++j) { float x = a0[j]; af[j] = f2bf(x > 0.f ? x : 0.f); }
#pragma unroll
    for (int j = 0; j < 4; ++j) { float x = a1[j]; af[4 + j] = f2bf(x > 0.f ? x : 0.f); }
    bf16x8 afrag = __builtin_bit_cast(bf16x8, af);
#pragma unroll
    for (int nn = 0; nn < 8; ++nn) {
      const int n = n0 + nn * 16 + l16;
      short8 bs = *(const short8*)(BT + (size_t)n * HID + kbase);
      acc[nn] = __builtin_amdgcn_mfma_f32_16x16x32_bf16(
          afrag, __builtin_bit_cast(bf16x8, bs), acc[nn], 0, 0, 0);
    }
  }
#pragma unroll
  for (int nn = 0; nn < 8; ++nn) {
    const int col = n0 + nn * 16 + l16;
#pragma unroll
    for (int r = 0; r < 4; ++r) {
      const int row = row0 + quad * 4 + r;
      if (row < n_nodes) GH[(size_t)row * NCAT + col] = f2bf(acc[nn][r]);
    }
  }
}

__global__ __launch_bounds__(256) void edge2_bf(
    const short* __restrict__ GH, const int* __restrict__ edges,
    const float* __restrict__ b1, const float* __restrict__ W2,
    const float* __restrict__ b2, float* __restrict__ out, int n_edges) {
  const int wave = threadIdx.x >> 6;
  const int lane = threadIdx.x & 63;
  const int w = blockIdx.x * 4 + wave;
  const int e0 = 2 * w;
  if (e0 >= n_edges) return;
  const bool has1 = (e0 + 1 < n_edges);
  const int j0 = lane * 8;
  const int u0 = edges[e0];
  const int v0 = edges[n_edges + e0];
  const int u1 = has1 ? edges[e0 + 1] : u0;
  const int v1 = has1 ? edges[n_edges + e0 + 1] : v0;
  short8 g0 = *(const short8*)(GH + (size_t)u0 * NCAT + j0);
  short8 h0 = *(const short8*)(GH + (size_t)v0 * NCAT + N1 + j0);
  short8 g1 = *(const short8*)(GH + (size_t)u1 * NCAT + j0);
  short8 h1 = *(const short8*)(GH + (size_t)v1 * NCAT + N1 + j0);
  float bv[8];
  {
    floatx4 t0 = *(const floatx4*)(b1 + j0);
    floatx4 t1 = *(const floatx4*)(b1 + j0 + 4);
#pragma unroll
    for (int j = 0; j < 4; ++j) { bv[j] = t0[j]; bv[4 + j] = t1[j]; }
  }
  float wv[16];
#pragma unroll
  for (int q = 0; q < 4; ++q) {
    floatx4 tt = *(const floatx4*)(W2 + (size_t)j0 * 2 + q * 4);
#pragma unroll
    for (int j = 0; j < 4; ++j) wv[q * 4 + j] = tt[j];
  }
  float s00 = 0.f, s01 = 0.f, s10 = 0.f, s11 = 0.f;
#pragma unroll
  for (int j = 0; j < 8; ++j) {
    float p0 = bf2f(g0[j]) + bf2f(h0[j]) + bv[j];
    p0 = p0 > 0.f ? p0 : 0.f;
    s00 += p0 * wv[2 * j];
    s01 += p0 * wv[2 * j + 1];
    float p1 = bf2f(g1[j]) + bf2f(h1[j]) + bv[j];
    p1 = p1 > 0.f ? p1 : 0.f;
    s10 += p1 * wv[2 * j];
    s11 += p1 * wv[2 * j + 1];
  }
#pragma unroll
  for (int off = 32; off > 0; off >>= 1) {
    s00 += __shfl_down(s00, off, 64);
    s01 += __shfl_down(s01, off, 64);
    s10 += __shfl_down(s10, off, 64);
    s11 += __shfl_down(s11, off, 64);
  }
  if (lane == 0) {
    out[2 * (size_t)e0]     = s00 + b2[0];
    out[2 * (size_t)e0 + 1] = s01 + b2[1];
    if (has1) {
      out[2 * (size_t)e0 + 2] = s10 + b2[0];
      out[2 * (size_t)e0 + 3] = s11 + b2[1];
    }
  }
}

// ---------------- tier-3 fallback: direct fp32 ----------------
__global__ __launch_bounds__(256) void slow_kernel(
    const float* __restrict__ feats, const int* __restrict__ edges,
    const float* __restrict__ W1, const float* __restrict__ b1,
    const float* __restrict__ W2, const float* __restrict__ b2,
    float* __restrict__ out, int n_edges) {
  const int wave = threadIdx.x >> 6;
  const int lane = threadIdx.x & 63;
  const int edge = blockIdx.x * 4 + wave;
  if (edge >= n_edges) return;
  const int u = edges[edge];
  const int v = edges[n_edges + edge];
  float f[4];
  f[0] = feats[(size_t)u * HID + lane];
  f[1] = feats[(size_t)u * HID + 64 + lane];
  f[2] = feats[(size_t)v * HID + lane];
  f[3] = feats[(size_t)v * HID + 64 + lane];
#pragma unroll
  for (int i = 0; i < 4; ++i) f[i] = f[i] > 0.f ? f[i] : 0.f;
  const int j0 = lane * 8;
  float acc[8];
#pragma unroll
  for (int j = 0; j < 8; ++j) acc[j] = 0.f;
#pragma unroll
  for (int seg = 0; seg < 4; ++seg) {
    float fs = f[seg];
    for (int k2 = 0; k2 < 64; ++k2) {
      float fk = __shfl(fs, k2, 64);
      const float* wr = W1 + (size_t)(seg * 64 + k2) * N1 + j0;
#pragma unroll
      for (int j = 0; j < 8; ++j) acc[j] += fk * wr[j];
    }
  }
  float s0 = 0.f, s1 = 0.f;
#pragma unroll
  for (int j = 0; j < 8; ++j) {
    float p = acc[j] + b1[j0 + j];
    p = p > 0.f ? p : 0.f;
    s0 += p * W2[(size_t)(j0 + j) * 2];
    s1 += p * W2[(size_t)(j0 + j) * 2 + 1];
  }
#pragma unroll
  for (int off = 32; off > 0; off >>= 1) {
    s0 += __shfl_down(s0, off, 64);
    s1 += __shfl_down(s1, off, 64);
  }
  if (lane == 0) {
    out[2 * (size_t)edge]     = s0 + b2[0];
    out[2 * (size_t)edge + 1] = s1 + b2[1];
  }
}

extern "C" void kernel_launch(void* const* d_in, const int* in_sizes, int n_in,
                              void* d_out, int out_size, void* d_ws, size_t ws_size,
                              hipStream_t stream) {
  const float* feats = (const float*)d_in[0];
  const int*   edges = (const int*)d_in[1];
  const float* W1    = (const float*)d_in[2];
  const float* b1    = (const float*)d_in[3];
  const float* W2    = (const float*)d_in[4];
  const float* b2    = (const float*)d_in[5];
  float* out = (float*)d_out;

  const int n_nodes = in_sizes[0] / HID;
  const int n_edges = in_sizes[1] / 2;

  const size_t bt_bytes   = (size_t)NCAT * HID * 2;       // 256 KiB
  const size_t misc_bytes = 4096;                         // W2T (2 KiB) + B1h (1 KiB)
  const size_t a_bytes    = (size_t)n_nodes * HID * 2;    // ~25.6 MB
  const size_t gh_bytes   = (size_t)n_nodes * NCAT * 2;   // ~204.8 MB

  if (ws_size >= bt_bytes + misc_bytes + a_bytes + gh_bytes) {
    f16* BT  = (f16*)d_ws;
    f16* W2T = (f16*)((char*)d_ws + bt_bytes);
    f16* B1h = (f16*)((char*)d_ws + bt_bytes + 2048);
    f16* A   = (f16*)((char*)d_ws + bt_bytes + misc_bytes);
    f16* GH  = (f16*)((char*)d_ws + bt_bytes + misc_bytes + a_bytes);
    conv_bt16<<<(NCAT * HID) / 256, 256, 0, stream>>>(W1, BT);
    conv_misc<<<6, 256, 0, stream>>>(W2, b1, W2T, B1h);
    const int total4 = n_nodes * HID / 4;
    prep_a16<<<(total4 + 255) / 256, 256, 0, stream>>>(feats, A, total4);
    dim3 grid(NCAT / 64, (n_nodes + 511) / 512);
    gemm4_kernel<<<grid, 256, 0, stream>>>(A, BT, B1h, GH, n_nodes);
    const int nwaves = (n_edges + 3) / 4;
    edge5_kernel<<<(nwaves + 3) / 4, 256, 0, stream>>>(GH, edges, W2T, b2, out, n_edges);
  } else if (ws_size >= bt_bytes + gh_bytes) {
    short* BT = (short*)d_ws;
    short* GH = (short*)((char*)d_ws + bt_bytes);
    conv_bt_bf<<<(NCAT * HID) / 256, 256, 0, stream>>>(W1, BT);
    dim3 grid((n_nodes + 63) / 64, NCAT / 128);
    gemm_bf<<<grid, 256, 0, stream>>>(feats, BT, GH, n_nodes);
    edge2_bf<<<((n_edges + 1) / 2 + 3) / 4, 256, 0, stream>>>(GH, edges, b1, W2, b2, out, n_edges);
  } else {
    slow_kernel<<<(n_edges + 3) / 4, 256, 0, stream>>>(feats, edges, W1, b1, W2, b2, out, n_edges);
  }
}

// Round 6
// 318.495 us; speedup vs baseline: 1.2883x; 1.0697x over previous
//
#include <hip/hip_runtime.h>
#include <hip/hip_bf16.h>
#include <stdint.h>

#define HID  128
#define N1   512
#define NCAT 1024
#define LDS_STRIDE 68   // 64 cols + 4 pad (f16) -> <=2-way bank conflicts (free)

typedef _Float16 f16;
typedef __attribute__((ext_vector_type(8))) _Float16 f16x8;
typedef __attribute__((ext_vector_type(4))) _Float16 f16x4;
typedef __attribute__((ext_vector_type(2))) _Float16 f16x2;
typedef __attribute__((ext_vector_type(8))) short   short8;
typedef __attribute__((ext_vector_type(4))) float   floatx4;
typedef __attribute__((ext_vector_type(2))) float   floatx2;

static __device__ __forceinline__ short f2bf(float x) {
  uint32_t u = __builtin_bit_cast(uint32_t, x);
  uint32_t r = (u + 0x7FFFu + ((u >> 16) & 1u)) >> 16;
  return (short)r;
}
static __device__ __forceinline__ float bf2f(short s) {
  uint32_t u = ((uint32_t)(uint16_t)s) << 16;
  return __builtin_bit_cast(float, u);
}
static __device__ __forceinline__ f16x2 pkrtz(float a, float b) {
  return __builtin_bit_cast(f16x2, __builtin_amdgcn_cvt_pkrtz(a, b));
}

// ---------------- tier-1 (fp16) pipeline ----------------

// Merged weight-prep: idx<131072 -> BT; next 1024 -> W2T; next 512 -> B1h
__global__ __launch_bounds__(256) void conv_all16(
    const float* __restrict__ W1, const float* __restrict__ W2,
    const float* __restrict__ b1, f16* __restrict__ BT,
    f16* __restrict__ W2T, f16* __restrict__ B1h) {
  int idx = blockIdx.x * 256 + threadIdx.x;
  if (idx < NCAT * HID) {
    int n = idx >> 7;
    int k = idx & 127;
    float w = (n < N1) ? W1[k * N1 + n] : W1[(k + HID) * N1 + (n - N1)];
    BT[idx] = (f16)w;
  } else if (idx < NCAT * HID + 1024) {
    int t = idx - NCAT * HID;
    int c = t >> 9;
    int j = t & 511;
    W2T[t] = (f16)W2[j * 2 + c];
  } else if (idx < NCAT * HID + 1536) {
    int j = idx - NCAT * HID - 1024;
    B1h[j] = (f16)b1[j];
  }
}

// A'[m][k] = f16(relu(feats[m][k]))
__global__ __launch_bounds__(256) void prep_a16(
    const float* __restrict__ feats, f16* __restrict__ A, int total4) {
  int idx = blockIdx.x * 256 + threadIdx.x;
  if (idx >= total4) return;
  floatx4 f = *(const floatx4*)(feats + (size_t)idx * 4);
  f16x4 o;
#pragma unroll
  for (int j = 0; j < 4; ++j) {
    float x = f[j]; x = x > 0.f ? x : 0.f;
    o[j] = (f16)x;
  }
  *(f16x4*)(A + (size_t)idx * 4) = o;
}

// GH[m][n] = sum_k A'[m][k]*BT[n][k] (+ b1[n] for n<512), f16 out.
// gemm5: gemm4 compute structure (wave = 128 rows x 64 cols, 8 m-tiles,
// register-resident B, 1-deep A prefetch) + LDS-coalesced epilogue:
// MFMA C-layout (8B/lane @ 2KB stride = partial-line stores) is transposed
// through wave-local LDS so each global_store_dwordx4 instruction writes
// 8 rows x 128B = 16 FULL 64B lines.
__global__ __launch_bounds__(256) void gemm5_kernel(
    const f16* __restrict__ A,      // (n_nodes,128)
    const f16* __restrict__ BT,     // (1024,128)
    const f16* __restrict__ B1h,    // (512,)
    f16* __restrict__ GH,           // (n_nodes,1024)
    int n_nodes) {
  __shared__ f16 lds[4][16 * LDS_STRIDE];   // 2176B per wave

  const int wave = threadIdx.x >> 6;
  const int lane = threadIdx.x & 63;
  const int quad = lane >> 4;
  const int l16  = lane & 15;
  const int c0 = blockIdx.x * 64;
  const int r0 = blockIdx.y * 512 + wave * 128;
  const bool hasB = (c0 < N1);
  f16* my = lds[wave];

  // B fragments (persistent, 64 VGPRs)
  f16x8 bfr[4][4];
#pragma unroll
  for (int nn = 0; nn < 4; ++nn) {
    const f16* brow = BT + (((size_t)(c0 + nn * 16 + l16)) << 7) + quad * 8;
#pragma unroll
    for (int kk = 0; kk < 4; ++kk)
      bfr[nn][kk] = *(const f16x8*)(brow + kk * 32);
  }

  // bias (f16)
  f16x4 bb[4];
#pragma unroll
  for (int nn = 0; nn < 4; ++nn) {
    const int colbase = (c0 + nn * 16 + quad * 4) & (N1 - 1);
    bb[nn] = *(const f16x4*)(B1h + colbase);
  }

  // epilogue output mapping: lane L -> row (L>>3), chunk (L&7)*8 f16 (16B)
  const int orow = lane >> 3;
  const int ochunk = (lane & 7) * 8;
  f16* lrd = my + orow * LDS_STRIDE + ochunk;

  // prefetch A for mt=0
  f16x8 anext[4];
  {
    int m = r0 + l16;
    if (m >= n_nodes) m = n_nodes - 1;
    const f16* arow = A + (((size_t)m) << 7) + quad * 8;
#pragma unroll
    for (int kk = 0; kk < 4; ++kk) anext[kk] = *(const f16x8*)(arow + kk * 32);
  }

#pragma unroll
  for (int mt = 0; mt < 8; ++mt) {
    f16x8 afr[4];
#pragma unroll
    for (int kk = 0; kk < 4; ++kk) afr[kk] = anext[kk];

    if (mt < 7) {
      int m = r0 + (mt + 1) * 16 + l16;
      if (m >= n_nodes) m = n_nodes - 1;
      const f16* arow = A + (((size_t)m) << 7) + quad * 8;
#pragma unroll
      for (int kk = 0; kk < 4; ++kk) anext[kk] = *(const f16x8*)(arow + kk * 32);
    }

    floatx4 acc[4];
#pragma unroll
    for (int nn = 0; nn < 4; ++nn) acc[nn] = (floatx4){0.f, 0.f, 0.f, 0.f};
#pragma unroll
    for (int kk = 0; kk < 4; ++kk)
#pragma unroll
      for (int nn = 0; nn < 4; ++nn)
        acc[nn] = __builtin_amdgcn_mfma_f32_16x16x32_f16(bfr[nn][kk], afr[kk], acc[nn], 0, 0, 0);

    // ---- epilogue: pack+bias -> LDS (C-layout) -> coalesced global ----
    // C-layout: lane holds row l16, cols c0+nn*16+quad*4..+3
#pragma unroll
    for (int nn = 0; nn < 4; ++nn) {
      f16x2 lo = pkrtz(acc[nn][0], acc[nn][1]);
      f16x2 hi = pkrtz(acc[nn][2], acc[nn][3]);
      f16x4 o = {lo[0], lo[1], hi[0], hi[1]};
      if (hasB) o = o + bb[nn];
      *(f16x4*)(my + l16 * LDS_STRIDE + nn * 16 + quad * 4) = o;
    }
    __builtin_amdgcn_s_waitcnt(0 /* vmcnt(0) lgkmcnt(0) exp */);
    // wave-local: no barrier needed; waitcnt orders ds_write before ds_read
    const int rbase = r0 + mt * 16;
    f16x8 r0v = *(const f16x8*)(lrd);
    f16x8 r1v = *(const f16x8*)(lrd + 8 * LDS_STRIDE);
    const int grow0 = rbase + orow;
    const int grow1 = rbase + 8 + orow;
    if (grow0 < n_nodes)
      *(f16x8*)(GH + (size_t)grow0 * NCAT + c0 + ochunk) = r0v;
    if (grow1 < n_nodes)
      *(f16x8*)(GH + (size_t)grow1 * NCAT + c0 + ochunk) = r1v;
  }
}

// Edge phase: out[e] = relu(G'[u] + H[v]) @ W2T + b2  (b1 folded into G').
// 16 lanes per edge, 4 edges per wave.
__global__ __launch_bounds__(256) void edge5_kernel(
    const f16* __restrict__ GH, const int* __restrict__ edges,
    const f16* __restrict__ W2T, const float* __restrict__ b2,
    float* __restrict__ out, int n_edges) {
  const int wave = threadIdx.x >> 6;
  const int lane = threadIdx.x & 63;
  const int sub  = lane >> 4;
  const int t    = lane & 15;
  const int e = (blockIdx.x * 4 + wave) * 4 + sub;
  const bool valid = (e < n_edges);
  const int ec = valid ? e : (n_edges - 1);

  const int u = edges[ec];
  const int v = edges[n_edges + ec];
  const f16* gp = GH + (size_t)u * NCAT + t * 8;
  const f16* hp = GH + (size_t)v * NCAT + N1 + t * 8;

  f16x8 g[4], h[4];
#pragma unroll
  for (int q = 0; q < 4; ++q) {
    g[q] = *(const f16x8*)(gp + q * 128);
    h[q] = *(const f16x8*)(hp + q * 128);
  }
  f16x8 w0[4], w1[4];
#pragma unroll
  for (int q = 0; q < 4; ++q) {
    w0[q] = *(const f16x8*)(W2T + q * 128 + t * 8);
    w1[q] = *(const f16x8*)(W2T + N1 + q * 128 + t * 8);
  }

  const f16x8 zero8 = {0, 0, 0, 0, 0, 0, 0, 0};
  float s0 = 0.f, s1 = 0.f;
#pragma unroll
  for (int q = 0; q < 4; ++q) {
    f16x8 z = g[q] + h[q];
    z = __builtin_elementwise_max(z, zero8);
#pragma unroll
    for (int i = 0; i < 4; ++i) {
      f16x2 zp = {z[2 * i], z[2 * i + 1]};
      f16x2 wp0 = {w0[q][2 * i], w0[q][2 * i + 1]};
      f16x2 wp1 = {w1[q][2 * i], w1[q][2 * i + 1]};
#if __has_builtin(__builtin_amdgcn_fdot2)
      s0 = __builtin_amdgcn_fdot2(__builtin_bit_cast(__fp16 __attribute__((ext_vector_type(2))), zp),
                                  __builtin_bit_cast(__fp16 __attribute__((ext_vector_type(2))), wp0),
                                  s0, false);
      s1 = __builtin_amdgcn_fdot2(__builtin_bit_cast(__fp16 __attribute__((ext_vector_type(2))), zp),
                                  __builtin_bit_cast(__fp16 __attribute__((ext_vector_type(2))), wp1),
                                  s1, false);
#else
      s0 += (float)zp[0] * (float)wp0[0] + (float)zp[1] * (float)wp0[1];
      s1 += (float)zp[0] * (float)wp1[0] + (float)zp[1] * (float)wp1[1];
#endif
    }
  }
#pragma unroll
  for (int off = 8; off > 0; off >>= 1) {
    s0 += __shfl_down(s0, off, 16);
    s1 += __shfl_down(s1, off, 16);
  }
  if (t == 0 && valid) {
    floatx2 o = {s0 + b2[0], s1 + b2[1]};
    *(floatx2*)(out + 2 * (size_t)e) = o;
  }
}

// ---------------- tier-2 fallback (bf16) ----------------

__global__ __launch_bounds__(256) void conv_bt_bf(
    const float* __restrict__ W1, short* __restrict__ BT) {
  int idx = blockIdx.x * 256 + threadIdx.x;
  int n = idx >> 7;
  int k = idx & 127;
  float w = (n < N1) ? W1[k * N1 + n] : W1[(k + HID) * N1 + (n - N1)];
  BT[idx] = f2bf(w);
}

typedef __attribute__((ext_vector_type(8))) __bf16 bf16x8;

__global__ __launch_bounds__(256) void gemm_bf(
    const float* __restrict__ feats, const short* __restrict__ BT,
    short* __restrict__ GH, int n_nodes) {
  const int wave = threadIdx.x >> 6;
  const int lane = threadIdx.x & 63;
  const int quad = lane >> 4;
  const int l16  = lane & 15;
  const int row0 = blockIdx.x * 64 + wave * 16;
  const int n0   = blockIdx.y * 128;
  const int m  = row0 + l16;
  const int mc = (m < n_nodes) ? m : (n_nodes - 1);
  const float* arow = feats + (size_t)mc * HID;
  floatx4 acc[8];
#pragma unroll
  for (int i = 0; i < 8; ++i) acc[i] = (floatx4){0.f, 0.f, 0.f, 0.f};
#pragma unroll
  for (int kk = 0; kk < 4; ++kk) {
    const int kbase = kk * 32 + quad * 8;
    floatx4 a0 = *(const floatx4*)(arow + kbase);
    floatx4 a1 = *(const floatx4*)(arow + kbase + 4);
    short8 af;
#pragma unroll
    for (int j = 0; j < 4; ++j) { float x = a0[j]; af[j] = f2bf(x > 0.f ? x : 0.f); }
#pragma unroll
    for (int j = 0; j < 4; ++j) { float x = a1[j]; af[4 + j] = f2bf(x > 0.f ? x : 0.f); }
    bf16x8 afrag = __builtin_bit_cast(bf16x8, af);
#pragma unroll
    for (int nn = 0; nn < 8; ++nn) {
      const int n = n0 + nn * 16 + l16;
      short8 bs = *(const short8*)(BT + (size_t)n * HID + kbase);
      acc[nn] = __builtin_amdgcn_mfma_f32_16x16x32_bf16(
          afrag, __builtin_bit_cast(bf16x8, bs), acc[nn], 0, 0, 0);
    }
  }
#pragma unroll
  for (int nn = 0; nn < 8; ++nn) {
    const int col = n0 + nn * 16 + l16;
#pragma unroll
    for (int r = 0; r < 4; ++r) {
      const int row = row0 + quad * 4 + r;
      if (row < n_nodes) GH[(size_t)row * NCAT + col] = f2bf(acc[nn][r]);
    }
  }
}

__global__ __launch_bounds__(256) void edge2_bf(
    const short* __restrict__ GH, const int* __restrict__ edges,
    const float* __restrict__ b1, const float* __restrict__ W2,
    const float* __restrict__ b2, float* __restrict__ out, int n_edges) {
  const int wave = threadIdx.x >> 6;
  const int lane = threadIdx.x & 63;
  const int w = blockIdx.x * 4 + wave;
  const int e0 = 2 * w;
  if (e0 >= n_edges) return;
  const bool has1 = (e0 + 1 < n_edges);
  const int j0 = lane * 8;
  const int u0 = edges[e0];
  const int v0 = edges[n_edges + e0];
  const int u1 = has1 ? edges[e0 + 1] : u0;
  const int v1 = has1 ? edges[n_edges + e0 + 1] : v0;
  short8 g0 = *(const short8*)(GH + (size_t)u0 * NCAT + j0);
  short8 h0 = *(const short8*)(GH + (size_t)v0 * NCAT + N1 + j0);
  short8 g1 = *(const short8*)(GH + (size_t)u1 * NCAT + j0);
  short8 h1 = *(const short8*)(GH + (size_t)v1 * NCAT + N1 + j0);
  float bv[8];
  {
    floatx4 t0 = *(const floatx4*)(b1 + j0);
    floatx4 t1 = *(const floatx4*)(b1 + j0 + 4);
#pragma unroll
    for (int j = 0; j < 4; ++j) { bv[j] = t0[j]; bv[4 + j] = t1[j]; }
  }
  float wv[16];
#pragma unroll
  for (int q = 0; q < 4; ++q) {
    floatx4 tt = *(const floatx4*)(W2 + (size_t)j0 * 2 + q * 4);
#pragma unroll
    for (int j = 0; j < 4; ++j) wv[q * 4 + j] = tt[j];
  }
  float s00 = 0.f, s01 = 0.f, s10 = 0.f, s11 = 0.f;
#pragma unroll
  for (int j = 0; j < 8; ++j) {
    float p0 = bf2f(g0[j]) + bf2f(h0[j]) + bv[j];
    p0 = p0 > 0.f ? p0 : 0.f;
    s00 += p0 * wv[2 * j];
    s01 += p0 * wv[2 * j + 1];
    float p1 = bf2f(g1[j]) + bf2f(h1[j]) + bv[j];
    p1 = p1 > 0.f ? p1 : 0.f;
    s10 += p1 * wv[2 * j];
    s11 += p1 * wv[2 * j + 1];
  }
#pragma unroll
  for (int off = 32; off > 0; off >>= 1) {
    s00 += __shfl_down(s00, off, 64);
    s01 += __shfl_down(s01, off, 64);
    s10 += __shfl_down(s10, off, 64);
    s11 += __shfl_down(s11, off, 64);
  }
  if (lane == 0) {
    out[2 * (size_t)e0]     = s00 + b2[0];
    out[2 * (size_t)e0 + 1] = s01 + b2[1];
    if (has1) {
      out[2 * (size_t)e0 + 2] = s10 + b2[0];
      out[2 * (size_t)e0 + 3] = s11 + b2[1];
    }
  }
}

// ---------------- tier-3 fallback: direct fp32 ----------------
__global__ __launch_bounds__(256) void slow_kernel(
    const float* __restrict__ feats, const int* __restrict__ edges,
    const float* __restrict__ W1, const float* __restrict__ b1,
    const float* __restrict__ W2, const float* __restrict__ b2,
    float* __restrict__ out, int n_edges) {
  const int wave = threadIdx.x >> 6;
  const int lane = threadIdx.x & 63;
  const int edge = blockIdx.x * 4 + wave;
  if (edge >= n_edges) return;
  const int u = edges[edge];
  const int v = edges[n_edges + edge];
  float f[4];
  f[0] = feats[(size_t)u * HID + lane];
  f[1] = feats[(size_t)u * HID + 64 + lane];
  f[2] = feats[(size_t)v * HID + lane];
  f[3] = feats[(size_t)v * HID + 64 + lane];
#pragma unroll
  for (int i = 0; i < 4; ++i) f[i] = f[i] > 0.f ? f[i] : 0.f;
  const int j0 = lane * 8;
  float acc[8];
#pragma unroll
  for (int j = 0; j < 8; ++j) acc[j] = 0.f;
#pragma unroll
  for (int seg = 0; seg < 4; ++seg) {
    float fs = f[seg];
    for (int k2 = 0; k2 < 64; ++k2) {
      float fk = __shfl(fs, k2, 64);
      const float* wr = W1 + (size_t)(seg * 64 + k2) * N1 + j0;
#pragma unroll
      for (int j = 0; j < 8; ++j) acc[j] += fk * wr[j];
    }
  }
  float s0 = 0.f, s1 = 0.f;
#pragma unroll
  for (int j = 0; j < 8; ++j) {
    float p = acc[j] + b1[j0 + j];
    p = p > 0.f ? p : 0.f;
    s0 += p * W2[(size_t)(j0 + j) * 2];
    s1 += p * W2[(size_t)(j0 + j) * 2 + 1];
  }
#pragma unroll
  for (int off = 32; off > 0; off >>= 1) {
    s0 += __shfl_down(s0, off, 64);
    s1 += __shfl_down(s1, off, 64);
  }
  if (lane == 0) {
    out[2 * (size_t)edge]     = s0 + b2[0];
    out[2 * (size_t)edge + 1] = s1 + b2[1];
  }
}

extern "C" void kernel_launch(void* const* d_in, const int* in_sizes, int n_in,
                              void* d_out, int out_size, void* d_ws, size_t ws_size,
                              hipStream_t stream) {
  const float* feats = (const float*)d_in[0];
  const int*   edges = (const int*)d_in[1];
  const float* W1    = (const float*)d_in[2];
  const float* b1    = (const float*)d_in[3];
  const float* W2    = (const float*)d_in[4];
  const float* b2    = (const float*)d_in[5];
  float* out = (float*)d_out;

  const int n_nodes = in_sizes[0] / HID;
  const int n_edges = in_sizes[1] / 2;

  const size_t bt_bytes   = (size_t)NCAT * HID * 2;       // 256 KiB
  const size_t misc_bytes = 4096;                         // W2T (2 KiB) + B1h (1 KiB)
  const size_t a_bytes    = (size_t)n_nodes * HID * 2;    // ~25.6 MB
  const size_t gh_bytes   = (size_t)n_nodes * NCAT * 2;   // ~204.8 MB

  if (ws_size >= bt_bytes + misc_bytes + a_bytes + gh_bytes) {
    f16* BT  = (f16*)d_ws;
    f16* W2T = (f16*)((char*)d_ws + bt_bytes);
    f16* B1h = (f16*)((char*)d_ws + bt_bytes + 2048);
    f16* A   = (f16*)((char*)d_ws + bt_bytes + misc_bytes);
    f16* GH  = (f16*)((char*)d_ws + bt_bytes + misc_bytes + a_bytes);
    conv_all16<<<(NCAT * HID + 1536 + 255) / 256, 256, 0, stream>>>(W1, W2, b1, BT, W2T, B1h);
    const int total4 = n_nodes * HID / 4;
    prep_a16<<<(total4 + 255) / 256, 256, 0, stream>>>(feats, A, total4);
    dim3 grid(NCAT / 64, (n_nodes + 511) / 512);
    gemm5_kernel<<<grid, 256, 0, stream>>>(A, BT, B1h, GH, n_nodes);
    const int nwaves = (n_edges + 3) / 4;
    edge5_kernel<<<(nwaves + 3) / 4, 256, 0, stream>>>(GH, edges, W2T, b2, out, n_edges);
  } else if (ws_size >= bt_bytes + gh_bytes) {
    short* BT = (short*)d_ws;
    short* GH = (short*)((char*)d_ws + bt_bytes);
    conv_bt_bf<<<(NCAT * HID) / 256, 256, 0, stream>>>(W1, BT);
    dim3 grid((n_nodes + 63) / 64, NCAT / 128);
    gemm_bf<<<grid, 256, 0, stream>>>(feats, BT, GH, n_nodes);
    edge2_bf<<<((n_edges + 1) / 2 + 3) / 4, 256, 0, stream>>>(GH, edges, b1, W2, b2, out, n_edges);
  } else {
    slow_kernel<<<(n_edges + 3) / 4, 256, 0, stream>>>(feats, edges, W1, b1, W2, b2, out, n_edges);
  }
}

// Round 7
// 316.004 us; speedup vs baseline: 1.2984x; 1.0079x over previous
//
#include <hip/hip_runtime.h>
#include <hip/hip_bf16.h>
#include <stdint.h>

#define HID  128
#define N1   512
#define NCAT 1024
#define LDS_STRIDE 68   // 64 cols + 4 pad (f16) -> <=2-way bank conflicts (free)

typedef _Float16 f16;
typedef __attribute__((ext_vector_type(8))) _Float16 f16x8;
typedef __attribute__((ext_vector_type(4))) _Float16 f16x4;
typedef __attribute__((ext_vector_type(2))) _Float16 f16x2;
typedef __attribute__((ext_vector_type(8))) short   short8;
typedef __attribute__((ext_vector_type(4))) float   floatx4;
typedef __attribute__((ext_vector_type(2))) float   floatx2;

static __device__ __forceinline__ short f2bf(float x) {
  uint32_t u = __builtin_bit_cast(uint32_t, x);
  uint32_t r = (u + 0x7FFFu + ((u >> 16) & 1u)) >> 16;
  return (short)r;
}
static __device__ __forceinline__ float bf2f(short s) {
  uint32_t u = ((uint32_t)(uint16_t)s) << 16;
  return __builtin_bit_cast(float, u);
}
static __device__ __forceinline__ f16x2 pkrtz(float a, float b) {
  return __builtin_bit_cast(f16x2, __builtin_amdgcn_cvt_pkrtz(a, b));
}

// ---------------- tier-1 (fp16) pipeline ----------------

// Merged prep: idx < total4 -> A' (relu+cvt, float4 granules);
// next 131072 -> BT; next 1024 -> W2T; next 512 -> B1h.
__global__ __launch_bounds__(256) void prep_all(
    const float* __restrict__ feats, const float* __restrict__ W1,
    const float* __restrict__ W2, const float* __restrict__ b1,
    f16* __restrict__ A, f16* __restrict__ BT,
    f16* __restrict__ W2T, f16* __restrict__ B1h, int total4) {
  int idx = blockIdx.x * 256 + threadIdx.x;
  if (idx < total4) {
    floatx4 f = *(const floatx4*)(feats + (size_t)idx * 4);
    f16x4 o;
#pragma unroll
    for (int j = 0; j < 4; ++j) {
      float x = f[j]; x = x > 0.f ? x : 0.f;
      o[j] = (f16)x;
    }
    *(f16x4*)(A + (size_t)idx * 4) = o;
    return;
  }
  int w = idx - total4;
  if (w < NCAT * HID) {
    int n = w >> 7;
    int k = w & 127;
    float wv = (n < N1) ? W1[k * N1 + n] : W1[(k + HID) * N1 + (n - N1)];
    BT[w] = (f16)wv;
  } else if (w < NCAT * HID + 1024) {
    int t = w - NCAT * HID;
    int c = t >> 9;
    int j = t & 511;
    W2T[t] = (f16)W2[j * 2 + c];
  } else if (w < NCAT * HID + 1536) {
    int j = w - NCAT * HID - 1024;
    B1h[j] = (f16)b1[j];
  }
}

// GH[m][n] = sum_k A'[m][k]*BT[n][k] (+ b1[n] for n<512), f16 out.
// gemm6: wave = 128 rows x 64 cols (8 m-tiles), register-resident B,
// 1-deep A prefetch, LDS-coalesced epilogue. The per-tile wait is
// lgkmcnt(0)-ONLY (0xC07F) so global stores stay pipelined across tiles
// and the A-prefetch is never drained (R6's waitcnt(0) bug).
__global__ __launch_bounds__(256) void gemm6_kernel(
    const f16* __restrict__ A,      // (n_nodes,128)
    const f16* __restrict__ BT,     // (1024,128)
    const f16* __restrict__ B1h,    // (512,)
    f16* __restrict__ GH,           // (n_nodes,1024)
    int n_nodes) {
  __shared__ f16 lds[4][16 * LDS_STRIDE];   // 2176B per wave

  const int wave = threadIdx.x >> 6;
  const int lane = threadIdx.x & 63;
  const int quad = lane >> 4;
  const int l16  = lane & 15;
  const int c0 = blockIdx.x * 64;
  const int r0 = blockIdx.y * 512 + wave * 128;
  const bool hasB = (c0 < N1);
  f16* my = lds[wave];

  // B fragments (persistent, 64 VGPRs)
  f16x8 bfr[4][4];
#pragma unroll
  for (int nn = 0; nn < 4; ++nn) {
    const f16* brow = BT + (((size_t)(c0 + nn * 16 + l16)) << 7) + quad * 8;
#pragma unroll
    for (int kk = 0; kk < 4; ++kk)
      bfr[nn][kk] = *(const f16x8*)(brow + kk * 32);
  }

  // bias (f16)
  f16x4 bb[4];
#pragma unroll
  for (int nn = 0; nn < 4; ++nn) {
    const int colbase = (c0 + nn * 16 + quad * 4) & (N1 - 1);
    bb[nn] = *(const f16x4*)(B1h + colbase);
  }

  // epilogue output mapping: lane L -> row (L>>3), chunk (L&7)*8 f16 (16B)
  const int orow = lane >> 3;
  const int ochunk = (lane & 7) * 8;
  f16* lrd = my + orow * LDS_STRIDE + ochunk;

  // prefetch A for mt=0
  f16x8 anext[4];
  {
    int m = r0 + l16;
    if (m >= n_nodes) m = n_nodes - 1;
    const f16* arow = A + (((size_t)m) << 7) + quad * 8;
#pragma unroll
    for (int kk = 0; kk < 4; ++kk) anext[kk] = *(const f16x8*)(arow + kk * 32);
  }

#pragma unroll
  for (int mt = 0; mt < 8; ++mt) {
    f16x8 afr[4];
#pragma unroll
    for (int kk = 0; kk < 4; ++kk) afr[kk] = anext[kk];

    if (mt < 7) {
      int m = r0 + (mt + 1) * 16 + l16;
      if (m >= n_nodes) m = n_nodes - 1;
      const f16* arow = A + (((size_t)m) << 7) + quad * 8;
#pragma unroll
      for (int kk = 0; kk < 4; ++kk) anext[kk] = *(const f16x8*)(arow + kk * 32);
    }

    floatx4 acc[4];
#pragma unroll
    for (int nn = 0; nn < 4; ++nn) acc[nn] = (floatx4){0.f, 0.f, 0.f, 0.f};
#pragma unroll
    for (int kk = 0; kk < 4; ++kk)
#pragma unroll
      for (int nn = 0; nn < 4; ++nn)
        acc[nn] = __builtin_amdgcn_mfma_f32_16x16x32_f16(bfr[nn][kk], afr[kk], acc[nn], 0, 0, 0);

    // ---- epilogue: pack+bias -> LDS (C-layout) -> coalesced global ----
#pragma unroll
    for (int nn = 0; nn < 4; ++nn) {
      f16x2 lo = pkrtz(acc[nn][0], acc[nn][1]);
      f16x2 hi = pkrtz(acc[nn][2], acc[nn][3]);
      f16x4 o = {lo[0], lo[1], hi[0], hi[1]};
      if (hasB) o = o + bb[nn];
      *(f16x4*)(my + l16 * LDS_STRIDE + nn * 16 + quad * 4) = o;
    }
    // lgkmcnt(0) ONLY (vmcnt=63, expcnt=7): DS ops are in-order within a
    // wave, so this orders ds_write -> ds_read without draining the
    // global-store / prefetch pipeline.
    __builtin_amdgcn_s_waitcnt(0xC07F);
    const int rbase = r0 + mt * 16;
    f16x8 r0v = *(const f16x8*)(lrd);
    f16x8 r1v = *(const f16x8*)(lrd + 8 * LDS_STRIDE);
    const int grow0 = rbase + orow;
    const int grow1 = rbase + 8 + orow;
    if (grow0 < n_nodes)
      *(f16x8*)(GH + (size_t)grow0 * NCAT + c0 + ochunk) = r0v;
    if (grow1 < n_nodes)
      *(f16x8*)(GH + (size_t)grow1 * NCAT + c0 + ochunk) = r1v;
  }
}

// Edge phase: out[e] = relu(G'[u] + H[v]) @ W2T + b2  (b1 folded into G').
// 16 lanes per edge, 4 edges per wave.
__global__ __launch_bounds__(256) void edge5_kernel(
    const f16* __restrict__ GH, const int* __restrict__ edges,
    const f16* __restrict__ W2T, const float* __restrict__ b2,
    float* __restrict__ out, int n_edges) {
  const int wave = threadIdx.x >> 6;
  const int lane = threadIdx.x & 63;
  const int sub  = lane >> 4;
  const int t    = lane & 15;
  const int e = (blockIdx.x * 4 + wave) * 4 + sub;
  const bool valid = (e < n_edges);
  const int ec = valid ? e : (n_edges - 1);

  const int u = edges[ec];
  const int v = edges[n_edges + ec];
  const f16* gp = GH + (size_t)u * NCAT + t * 8;
  const f16* hp = GH + (size_t)v * NCAT + N1 + t * 8;

  f16x8 g[4], h[4];
#pragma unroll
  for (int q = 0; q < 4; ++q) {
    g[q] = *(const f16x8*)(gp + q * 128);
    h[q] = *(const f16x8*)(hp + q * 128);
  }
  f16x8 w0[4], w1[4];
#pragma unroll
  for (int q = 0; q < 4; ++q) {
    w0[q] = *(const f16x8*)(W2T + q * 128 + t * 8);
    w1[q] = *(const f16x8*)(W2T + N1 + q * 128 + t * 8);
  }

  const f16x8 zero8 = {0, 0, 0, 0, 0, 0, 0, 0};
  float s0 = 0.f, s1 = 0.f;
#pragma unroll
  for (int q = 0; q < 4; ++q) {
    f16x8 z = g[q] + h[q];
    z = __builtin_elementwise_max(z, zero8);
#pragma unroll
    for (int i = 0; i < 4; ++i) {
      f16x2 zp = {z[2 * i], z[2 * i + 1]};
      f16x2 wp0 = {w0[q][2 * i], w0[q][2 * i + 1]};
      f16x2 wp1 = {w1[q][2 * i], w1[q][2 * i + 1]};
#if __has_builtin(__builtin_amdgcn_fdot2)
      s0 = __builtin_amdgcn_fdot2(__builtin_bit_cast(__fp16 __attribute__((ext_vector_type(2))), zp),
                                  __builtin_bit_cast(__fp16 __attribute__((ext_vector_type(2))), wp0),
                                  s0, false);
      s1 = __builtin_amdgcn_fdot2(__builtin_bit_cast(__fp16 __attribute__((ext_vector_type(2))), zp),
                                  __builtin_bit_cast(__fp16 __attribute__((ext_vector_type(2))), wp1),
                                  s1, false);
#else
      s0 += (float)zp[0] * (float)wp0[0] + (float)zp[1] * (float)wp0[1];
      s1 += (float)zp[0] * (float)wp1[0] + (float)zp[1] * (float)wp1[1];
#endif
    }
  }
#pragma unroll
  for (int off = 8; off > 0; off >>= 1) {
    s0 += __shfl_down(s0, off, 16);
    s1 += __shfl_down(s1, off, 16);
  }
  if (t == 0 && valid) {
    floatx2 o = {s0 + b2[0], s1 + b2[1]};
    *(floatx2*)(out + 2 * (size_t)e) = o;
  }
}

// ---------------- tier-2 fallback (bf16) ----------------

__global__ __launch_bounds__(256) void conv_bt_bf(
    const float* __restrict__ W1, short* __restrict__ BT) {
  int idx = blockIdx.x * 256 + threadIdx.x;
  int n = idx >> 7;
  int k = idx & 127;
  float w = (n < N1) ? W1[k * N1 + n] : W1[(k + HID) * N1 + (n - N1)];
  BT[idx] = f2bf(w);
}

typedef __attribute__((ext_vector_type(8))) __bf16 bf16x8;

__global__ __launch_bounds__(256) void gemm_bf(
    const float* __restrict__ feats, const short* __restrict__ BT,
    short* __restrict__ GH, int n_nodes) {
  const int wave = threadIdx.x >> 6;
  const int lane = threadIdx.x & 63;
  const int quad = lane >> 4;
  const int l16  = lane & 15;
  const int row0 = blockIdx.x * 64 + wave * 16;
  const int n0   = blockIdx.y * 128;
  const int m  = row0 + l16;
  const int mc = (m < n_nodes) ? m : (n_nodes - 1);
  const float* arow = feats + (size_t)mc * HID;
  floatx4 acc[8];
#pragma unroll
  for (int i = 0; i < 8; ++i) acc[i] = (floatx4){0.f, 0.f, 0.f, 0.f};
#pragma unroll
  for (int kk = 0; kk < 4; ++kk) {
    const int kbase = kk * 32 + quad * 8;
    floatx4 a0 = *(const floatx4*)(arow + kbase);
    floatx4 a1 = *(const floatx4*)(arow + kbase + 4);
    short8 af;
#pragma unroll
    for (int j = 0; j < 4; ++j) { float x = a0[j]; af[j] = f2bf(x > 0.f ? x : 0.f); }
#pragma unroll
    for (int j = 0; j < 4; ++j) { float x = a1[j]; af[4 + j] = f2bf(x > 0.f ? x : 0.f); }
    bf16x8 afrag = __builtin_bit_cast(bf16x8, af);
#pragma unroll
    for (int nn = 0; nn < 8; ++nn) {
      const int n = n0 + nn * 16 + l16;
      short8 bs = *(const short8*)(BT + (size_t)n * HID + kbase);
      acc[nn] = __builtin_amdgcn_mfma_f32_16x16x32_bf16(
          afrag, __builtin_bit_cast(bf16x8, bs), acc[nn], 0, 0, 0);
    }
  }
#pragma unroll
  for (int nn = 0; nn < 8; ++nn) {
    const int col = n0 + nn * 16 + l16;
#pragma unroll
    for (int r = 0; r < 4; ++r) {
      const int row = row0 + quad * 4 + r;
      if (row < n_nodes) GH[(size_t)row * NCAT + col] = f2bf(acc[nn][r]);
    }
  }
}

__global__ __launch_bounds__(256) void edge2_bf(
    const short* __restrict__ GH, const int* __restrict__ edges,
    const float* __restrict__ b1, const float* __restrict__ W2,
    const float* __restrict__ b2, float* __restrict__ out, int n_edges) {
  const int wave = threadIdx.x >> 6;
  const int lane = threadIdx.x & 63;
  const int w = blockIdx.x * 4 + wave;
  const int e0 = 2 * w;
  if (e0 >= n_edges) return;
  const bool has1 = (e0 + 1 < n_edges);
  const int j0 = lane * 8;
  const int u0 = edges[e0];
  const int v0 = edges[n_edges + e0];
  const int u1 = has1 ? edges[e0 + 1] : u0;
  const int v1 = has1 ? edges[n_edges + e0 + 1] : v0;
  short8 g0 = *(const short8*)(GH + (size_t)u0 * NCAT + j0);
  short8 h0 = *(const short8*)(GH + (size_t)v0 * NCAT + N1 + j0);
  short8 g1 = *(const short8*)(GH + (size_t)u1 * NCAT + j0);
  short8 h1 = *(const short8*)(GH + (size_t)v1 * NCAT + N1 + j0);
  float bv[8];
  {
    floatx4 t0 = *(const floatx4*)(b1 + j0);
    floatx4 t1 = *(const floatx4*)(b1 + j0 + 4);
#pragma unroll
    for (int j = 0; j < 4; ++j) { bv[j] = t0[j]; bv[4 + j] = t1[j]; }
  }
  float wv[16];
#pragma unroll
  for (int q = 0; q < 4; ++q) {
    floatx4 tt = *(const floatx4*)(W2 + (size_t)j0 * 2 + q * 4);
#pragma unroll
    for (int j = 0; j < 4; ++j) wv[q * 4 + j] = tt[j];
  }
  float s00 = 0.f, s01 = 0.f, s10 = 0.f, s11 = 0.f;
#pragma unroll
  for (int j = 0; j < 8; ++j) {
    float p0 = bf2f(g0[j]) + bf2f(h0[j]) + bv[j];
    p0 = p0 > 0.f ? p0 : 0.f;
    s00 += p0 * wv[2 * j];
    s01 += p0 * wv[2 * j + 1];
    float p1 = bf2f(g1[j]) + bf2f(h1[j]) + bv[j];
    p1 = p1 > 0.f ? p1 : 0.f;
    s10 += p1 * wv[2 * j];
    s11 += p1 * wv[2 * j + 1];
  }
#pragma unroll
  for (int off = 32; off > 0; off >>= 1) {
    s00 += __shfl_down(s00, off, 64);
    s01 += __shfl_down(s01, off, 64);
    s10 += __shfl_down(s10, off, 64);
    s11 += __shfl_down(s11, off, 64);
  }
  if (lane == 0) {
    out[2 * (size_t)e0]     = s00 + b2[0];
    out[2 * (size_t)e0 + 1] = s01 + b2[1];
    if (has1) {
      out[2 * (size_t)e0 + 2] = s10 + b2[0];
      out[2 * (size_t)e0 + 3] = s11 + b2[1];
    }
  }
}

// ---------------- tier-3 fallback: direct fp32 ----------------
__global__ __launch_bounds__(256) void slow_kernel(
    const float* __restrict__ feats, const int* __restrict__ edges,
    const float* __restrict__ W1, const float* __restrict__ b1,
    const float* __restrict__ W2, const float* __restrict__ b2,
    float* __restrict__ out, int n_edges) {
  const int wave = threadIdx.x >> 6;
  const int lane = threadIdx.x & 63;
  const int edge = blockIdx.x * 4 + wave;
  if (edge >= n_edges) return;
  const int u = edges[edge];
  const int v = edges[n_edges + edge];
  float f[4];
  f[0] = feats[(size_t)u * HID + lane];
  f[1] = feats[(size_t)u * HID + 64 + lane];
  f[2] = feats[(size_t)v * HID + lane];
  f[3] = feats[(size_t)v * HID + 64 + lane];
#pragma unroll
  for (int i = 0; i < 4; ++i) f[i] = f[i] > 0.f ? f[i] : 0.f;
  const int j0 = lane * 8;
  float acc[8];
#pragma unroll
  for (int j = 0; j < 8; ++j) acc[j] = 0.f;
#pragma unroll
  for (int seg = 0; seg < 4; ++seg) {
    float fs = f[seg];
    for (int k2 = 0; k2 < 64; ++k2) {
      float fk = __shfl(fs, k2, 64);
      const float* wr = W1 + (size_t)(seg * 64 + k2) * N1 + j0;
#pragma unroll
      for (int j = 0; j < 8; ++j) acc[j] += fk * wr[j];
    }
  }
  float s0 = 0.f, s1 = 0.f;
#pragma unroll
  for (int j = 0; j < 8; ++j) {
    float p = acc[j] + b1[j0 + j];
    p = p > 0.f ? p : 0.f;
    s0 += p * W2[(size_t)(j0 + j) * 2];
    s1 += p * W2[(size_t)(j0 + j) * 2 + 1];
  }
#pragma unroll
  for (int off = 32; off > 0; off >>= 1) {
    s0 += __shfl_down(s0, off, 64);
    s1 += __shfl_down(s1, off, 64);
  }
  if (lane == 0) {
    out[2 * (size_t)edge]     = s0 + b2[0];
    out[2 * (size_t)edge + 1] = s1 + b2[1];
  }
}

extern "C" void kernel_launch(void* const* d_in, const int* in_sizes, int n_in,
                              void* d_out, int out_size, void* d_ws, size_t ws_size,
                              hipStream_t stream) {
  const float* feats = (const float*)d_in[0];
  const int*   edges = (const int*)d_in[1];
  const float* W1    = (const float*)d_in[2];
  const float* b1    = (const float*)d_in[3];
  const float* W2    = (const float*)d_in[4];
  const float* b2    = (const float*)d_in[5];
  float* out = (float*)d_out;

  const int n_nodes = in_sizes[0] / HID;
  const int n_edges = in_sizes[1] / 2;

  const size_t bt_bytes   = (size_t)NCAT * HID * 2;       // 256 KiB
  const size_t misc_bytes = 4096;                         // W2T (2 KiB) + B1h (1 KiB)
  const size_t a_bytes    = (size_t)n_nodes * HID * 2;    // ~25.6 MB
  const size_t gh_bytes   = (size_t)n_nodes * NCAT * 2;   // ~204.8 MB

  if (ws_size >= bt_bytes + misc_bytes + a_bytes + gh_bytes) {
    f16* BT  = (f16*)d_ws;
    f16* W2T = (f16*)((char*)d_ws + bt_bytes);
    f16* B1h = (f16*)((char*)d_ws + bt_bytes + 2048);
    f16* A   = (f16*)((char*)d_ws + bt_bytes + misc_bytes);
    f16* GH  = (f16*)((char*)d_ws + bt_bytes + misc_bytes + a_bytes);
    const int total4 = n_nodes * HID / 4;
    const int prep_total = total4 + NCAT * HID + 1536;
    prep_all<<<(prep_total + 255) / 256, 256, 0, stream>>>(
        feats, W1, W2, b1, A, BT, W2T, B1h, total4);
    dim3 grid(NCAT / 64, (n_nodes + 511) / 512);
    gemm6_kernel<<<grid, 256, 0, stream>>>(A, BT, B1h, GH, n_nodes);
    const int nwaves = (n_edges + 3) / 4;
    edge5_kernel<<<(nwaves + 3) / 4, 256, 0, stream>>>(GH, edges, W2T, b2, out, n_edges);
  } else if (ws_size >= bt_bytes + gh_bytes) {
    short* BT = (short*)d_ws;
    short* GH = (short*)((char*)d_ws + bt_bytes);
    conv_bt_bf<<<(NCAT * HID) / 256, 256, 0, stream>>>(W1, BT);
    dim3 grid((n_nodes + 63) / 64, NCAT / 128);
    gemm_bf<<<grid, 256, 0, stream>>>(feats, BT, GH, n_nodes);
    edge2_bf<<<((n_edges + 1) / 2 + 3) / 4, 256, 0, stream>>>(GH, edges, b1, W2, b2, out, n_edges);
  } else {
    slow_kernel<<<(n_edges + 3) / 4, 256, 0, stream>>>(feats, edges, W1, b1, W2, b2, out, n_edges);
  }
}

// Round 8
// 314.205 us; speedup vs baseline: 1.3059x; 1.0057x over previous
//
#include <hip/hip_runtime.h>
#include <hip/hip_bf16.h>
#include <stdint.h>

#define HID  128
#define N1   512
#define NCAT 1024
#define LDS_STRIDE 68   // 64 cols + 4 pad (f16) -> <=2-way bank conflicts (free)

typedef _Float16 f16;
typedef __attribute__((ext_vector_type(8))) _Float16 f16x8;
typedef __attribute__((ext_vector_type(4))) _Float16 f16x4;
typedef __attribute__((ext_vector_type(2))) _Float16 f16x2;
typedef __attribute__((ext_vector_type(8))) short   short8;
typedef __attribute__((ext_vector_type(4))) float   floatx4;
typedef __attribute__((ext_vector_type(2))) float   floatx2;

static __device__ __forceinline__ short f2bf(float x) {
  uint32_t u = __builtin_bit_cast(uint32_t, x);
  uint32_t r = (u + 0x7FFFu + ((u >> 16) & 1u)) >> 16;
  return (short)r;
}
static __device__ __forceinline__ float bf2f(short s) {
  uint32_t u = ((uint32_t)(uint16_t)s) << 16;
  return __builtin_bit_cast(float, u);
}
static __device__ __forceinline__ f16x2 pkrtz(float a, float b) {
  return __builtin_bit_cast(f16x2, __builtin_amdgcn_cvt_pkrtz(a, b));
}
typedef __fp16 __attribute__((ext_vector_type(2))) fp16v2;
static __device__ __forceinline__ float fdot2(f16x2 a, f16x2 b, float c) {
#if __has_builtin(__builtin_amdgcn_fdot2)
  return __builtin_amdgcn_fdot2(__builtin_bit_cast(fp16v2, a),
                                __builtin_bit_cast(fp16v2, b), c, false);
#else
  return c + (float)a[0] * (float)b[0] + (float)a[1] * (float)b[1];
#endif
}

// ---------------- tier-1 (fp16) pipeline ----------------

// Merged prep: idx < total4 -> A' (relu+cvt, float4 granules);
// next 131072 -> BT; next 1024 -> W2T; next 512 -> B1h.
__global__ __launch_bounds__(256) void prep_all(
    const float* __restrict__ feats, const float* __restrict__ W1,
    const float* __restrict__ W2, const float* __restrict__ b1,
    f16* __restrict__ A, f16* __restrict__ BT,
    f16* __restrict__ W2T, f16* __restrict__ B1h, int total4) {
  int idx = blockIdx.x * 256 + threadIdx.x;
  if (idx < total4) {
    floatx4 f = *(const floatx4*)(feats + (size_t)idx * 4);
    f16x4 o;
#pragma unroll
    for (int j = 0; j < 4; ++j) {
      float x = f[j]; x = x > 0.f ? x : 0.f;
      o[j] = (f16)x;
    }
    *(f16x4*)(A + (size_t)idx * 4) = o;
    return;
  }
  int w = idx - total4;
  if (w < NCAT * HID) {
    int n = w >> 7;
    int k = w & 127;
    float wv = (n < N1) ? W1[k * N1 + n] : W1[(k + HID) * N1 + (n - N1)];
    BT[w] = (f16)wv;
  } else if (w < NCAT * HID + 1024) {
    int t = w - NCAT * HID;
    int c = t >> 9;
    int j = t & 511;
    W2T[t] = (f16)W2[j * 2 + c];
  } else if (w < NCAT * HID + 1536) {
    int j = w - NCAT * HID - 1024;
    B1h[j] = (f16)b1[j];
  }
}

// GH[m][n] = sum_k A'[m][k]*BT[n][k] (+ b1[n] for n<512), f16 out.
// gemm7: wave = 128 rows x 64 cols (8 m-tiles), register-resident B,
// **2-deep A prefetch ring** (loads for mt+1 AND mt+2 always in flight,
// ~600+ cyc latency coverage vs ~300 for the old 1-deep scheme),
// LDS-coalesced epilogue with lgkm-only wait.
__global__ __launch_bounds__(256) void gemm7_kernel(
    const f16* __restrict__ A,      // (n_nodes,128)
    const f16* __restrict__ BT,     // (1024,128)
    const f16* __restrict__ B1h,    // (512,)
    f16* __restrict__ GH,           // (n_nodes,1024)
    int n_nodes) {
  __shared__ f16 lds[4][16 * LDS_STRIDE];   // 2176B per wave

  const int wave = threadIdx.x >> 6;
  const int lane = threadIdx.x & 63;
  const int quad = lane >> 4;
  const int l16  = lane & 15;
  const int c0 = blockIdx.x * 64;
  const int r0 = blockIdx.y * 512 + wave * 128;
  const bool hasB = (c0 < N1);
  f16* my = lds[wave];

  // B fragments (persistent, 64 VGPRs)
  f16x8 bfr[4][4];
#pragma unroll
  for (int nn = 0; nn < 4; ++nn) {
    const f16* brow = BT + (((size_t)(c0 + nn * 16 + l16)) << 7) + quad * 8;
#pragma unroll
    for (int kk = 0; kk < 4; ++kk)
      bfr[nn][kk] = *(const f16x8*)(brow + kk * 32);
  }

  // bias (f16)
  f16x4 bb[4];
#pragma unroll
  for (int nn = 0; nn < 4; ++nn) {
    const int colbase = (c0 + nn * 16 + quad * 4) & (N1 - 1);
    bb[nn] = *(const f16x4*)(B1h + colbase);
  }

  // epilogue output mapping: lane L -> row (L>>3), chunk (L&7)*8 f16 (16B)
  const int orow = lane >> 3;
  const int ochunk = (lane & 7) * 8;
  f16* lrd = my + orow * LDS_STRIDE + ochunk;

  // 2-deep prefetch ring: slots for tiles mt and mt+1 resident/incoming.
  f16x8 ring[2][4];
#pragma unroll
  for (int p = 0; p < 2; ++p) {
    int m = r0 + p * 16 + l16;
    if (m >= n_nodes) m = n_nodes - 1;
    const f16* arow = A + (((size_t)m) << 7) + quad * 8;
#pragma unroll
    for (int kk = 0; kk < 4; ++kk) ring[p][kk] = *(const f16x8*)(arow + kk * 32);
  }

#pragma unroll
  for (int mt = 0; mt < 8; ++mt) {
    // consume slot (copy frees the slot for the mt+2 prefetch)
    f16x8 afr[4];
#pragma unroll
    for (int kk = 0; kk < 4; ++kk) afr[kk] = ring[mt & 1][kk];

    if (mt < 6) {   // prefetch tile mt+2 into the just-freed slot
      int m = r0 + (mt + 2) * 16 + l16;
      if (m >= n_nodes) m = n_nodes - 1;
      const f16* arow = A + (((size_t)m) << 7) + quad * 8;
#pragma unroll
      for (int kk = 0; kk < 4; ++kk) ring[mt & 1][kk] = *(const f16x8*)(arow + kk * 32);
    }

    floatx4 acc[4];
#pragma unroll
    for (int nn = 0; nn < 4; ++nn) acc[nn] = (floatx4){0.f, 0.f, 0.f, 0.f};
#pragma unroll
    for (int kk = 0; kk < 4; ++kk)
#pragma unroll
      for (int nn = 0; nn < 4; ++nn)
        acc[nn] = __builtin_amdgcn_mfma_f32_16x16x32_f16(bfr[nn][kk], afr[kk], acc[nn], 0, 0, 0);

    // ---- epilogue: pack+bias -> LDS (C-layout) -> coalesced global ----
#pragma unroll
    for (int nn = 0; nn < 4; ++nn) {
      f16x2 lo = pkrtz(acc[nn][0], acc[nn][1]);
      f16x2 hi = pkrtz(acc[nn][2], acc[nn][3]);
      f16x4 o = {lo[0], lo[1], hi[0], hi[1]};
      if (hasB) o = o + bb[nn];
      *(f16x4*)(my + l16 * LDS_STRIDE + nn * 16 + quad * 4) = o;
    }
    // lgkmcnt(0) only: orders ds_write -> ds_read without draining the
    // global-store / prefetch pipeline. DS ops are in-order per wave, so
    // next tile's ds_writes can't pass this tile's ds_reads.
    __builtin_amdgcn_s_waitcnt(0xC07F);
    const int rbase = r0 + mt * 16;
    f16x8 r0v = *(const f16x8*)(lrd);
    f16x8 r1v = *(const f16x8*)(lrd + 8 * LDS_STRIDE);
    const int grow0 = rbase + orow;
    const int grow1 = rbase + 8 + orow;
    if (grow0 < n_nodes)
      *(f16x8*)(GH + (size_t)grow0 * NCAT + c0 + ochunk) = r0v;
    if (grow1 < n_nodes)
      *(f16x8*)(GH + (size_t)grow1 * NCAT + c0 + ochunk) = r1v;
  }
}

// Edge phase: out[e] = relu(G'[u] + H[v]) @ W2T + b2  (b1 folded into G').
// edge7: 16 lanes per edge-PAIR group, 2 consecutive edges per group
// (8 edges/wave). All 16 gather loads (256B/lane) issued up front; W2
// registers shared between the paired edges; paired dwordx4 output store.
__global__ __launch_bounds__(256) void edge7_kernel(
    const f16* __restrict__ GH, const int* __restrict__ edges,
    const f16* __restrict__ W2T, const float* __restrict__ b2,
    float* __restrict__ out, int n_edges) {
  const int wave = threadIdx.x >> 6;
  const int lane = threadIdx.x & 63;
  const int sub  = lane >> 4;   // pair-group within wave (0..3)
  const int t    = lane & 15;   // lane within group
  const int grp = (blockIdx.x * 4 + wave) * 4 + sub;   // pair index
  const int e0 = grp * 2;
  const int e1 = e0 + 1;
  const bool v0 = (e0 < n_edges);
  const bool v1 = (e1 < n_edges);
  const int ec0 = v0 ? e0 : (n_edges - 1);
  const int ec1 = v1 ? e1 : (n_edges - 1);

  const int uA = edges[ec0];
  const int vA = edges[n_edges + ec0];
  const int uB = edges[ec1];
  const int vB = edges[n_edges + ec1];

  const f16* gpA = GH + (size_t)uA * NCAT + t * 8;
  const f16* hpA = GH + (size_t)vA * NCAT + N1 + t * 8;
  const f16* gpB = GH + (size_t)uB * NCAT + t * 8;
  const f16* hpB = GH + (size_t)vB * NCAT + N1 + t * 8;

  // 16 outstanding 16B gathers per lane (256B/lane, 16KB/wave)
  f16x8 gA[4], hA[4], gB[4], hB[4];
#pragma unroll
  for (int q = 0; q < 4; ++q) {
    gA[q] = *(const f16x8*)(gpA + q * 128);
    hA[q] = *(const f16x8*)(hpA + q * 128);
    gB[q] = *(const f16x8*)(gpB + q * 128);
    hB[q] = *(const f16x8*)(hpB + q * 128);
  }
  // W2 slices (L1-hot, shared by both edges of the pair)
  f16x8 w0[4], w1[4];
#pragma unroll
  for (int q = 0; q < 4; ++q) {
    w0[q] = *(const f16x8*)(W2T + q * 128 + t * 8);
    w1[q] = *(const f16x8*)(W2T + N1 + q * 128 + t * 8);
  }

  const f16x8 zero8 = {0, 0, 0, 0, 0, 0, 0, 0};
  float sA0 = 0.f, sA1 = 0.f, sB0 = 0.f, sB1 = 0.f;
#pragma unroll
  for (int q = 0; q < 4; ++q) {
    f16x8 zA = gA[q] + hA[q];
    zA = __builtin_elementwise_max(zA, zero8);
    f16x8 zB = gB[q] + hB[q];
    zB = __builtin_elementwise_max(zB, zero8);
#pragma unroll
    for (int i = 0; i < 4; ++i) {
      f16x2 zpA = {zA[2 * i], zA[2 * i + 1]};
      f16x2 zpB = {zB[2 * i], zB[2 * i + 1]};
      f16x2 wp0 = {w0[q][2 * i], w0[q][2 * i + 1]};
      f16x2 wp1 = {w1[q][2 * i], w1[q][2 * i + 1]};
      sA0 = fdot2(zpA, wp0, sA0);
      sA1 = fdot2(zpA, wp1, sA1);
      sB0 = fdot2(zpB, wp0, sB0);
      sB1 = fdot2(zpB, wp1, sB1);
    }
  }
#pragma unroll
  for (int off = 8; off > 0; off >>= 1) {
    sA0 += __shfl_down(sA0, off, 16);
    sA1 += __shfl_down(sA1, off, 16);
    sB0 += __shfl_down(sB0, off, 16);
    sB1 += __shfl_down(sB1, off, 16);
  }
  if (t == 0) {
    const float bb0 = b2[0], bb1 = b2[1];
    if (v0 && v1) {
      floatx4 o = {sA0 + bb0, sA1 + bb1, sB0 + bb0, sB1 + bb1};
      *(floatx4*)(out + (size_t)4 * grp) = o;
    } else if (v0) {
      floatx2 o = {sA0 + bb0, sA1 + bb1};
      *(floatx2*)(out + 2 * (size_t)e0) = o;
    }
  }
}

// ---------------- tier-2 fallback (bf16) ----------------

__global__ __launch_bounds__(256) void conv_bt_bf(
    const float* __restrict__ W1, short* __restrict__ BT) {
  int idx = blockIdx.x * 256 + threadIdx.x;
  int n = idx >> 7;
  int k = idx & 127;
  float w = (n < N1) ? W1[k * N1 + n] : W1[(k + HID) * N1 + (n - N1)];
  BT[idx] = f2bf(w);
}

typedef __attribute__((ext_vector_type(8))) __bf16 bf16x8;

__global__ __launch_bounds__(256) void gemm_bf(
    const float* __restrict__ feats, const short* __restrict__ BT,
    short* __restrict__ GH, int n_nodes) {
  const int wave = threadIdx.x >> 6;
  const int lane = threadIdx.x & 63;
  const int quad = lane >> 4;
  const int l16  = lane & 15;
  const int row0 = blockIdx.x * 64 + wave * 16;
  const int n0   = blockIdx.y * 128;
  const int m  = row0 + l16;
  const int mc = (m < n_nodes) ? m : (n_nodes - 1);
  const float* arow = feats + (size_t)mc * HID;
  floatx4 acc[8];
#pragma unroll
  for (int i = 0; i < 8; ++i) acc[i] = (floatx4){0.f, 0.f, 0.f, 0.f};
#pragma unroll
  for (int kk = 0; kk < 4; ++kk) {
    const int kbase = kk * 32 + quad * 8;
    floatx4 a0 = *(const floatx4*)(arow + kbase);
    floatx4 a1 = *(const floatx4*)(arow + kbase + 4);
    short8 af;
#pragma unroll
    for (int j = 0; j < 4; ++j) { float x = a0[j]; af[j] = f2bf(x > 0.f ? x : 0.f); }
#pragma unroll
    for (int j = 0; j < 4; ++j) { float x = a1[j]; af[4 + j] = f2bf(x > 0.f ? x : 0.f); }
    bf16x8 afrag = __builtin_bit_cast(bf16x8, af);
#pragma unroll
    for (int nn = 0; nn < 8; ++nn) {
      const int n = n0 + nn * 16 + l16;
      short8 bs = *(const short8*)(BT + (size_t)n * HID + kbase);
      acc[nn] = __builtin_amdgcn_mfma_f32_16x16x32_bf16(
          afrag, __builtin_bit_cast(bf16x8, bs), acc[nn], 0, 0, 0);
    }
  }
#pragma unroll
  for (int nn = 0; nn < 8; ++nn) {
    const int col = n0 + nn * 16 + l16;
#pragma unroll
    for (int r = 0; r < 4; ++r) {
      const int row = row0 + quad * 4 + r;
      if (row < n_nodes) GH[(size_t)row * NCAT + col] = f2bf(acc[nn][r]);
    }
  }
}

__global__ __launch_bounds__(256) void edge2_bf(
    const short* __restrict__ GH, const int* __restrict__ edges,
    const float* __restrict__ b1, const float* __restrict__ W2,
    const float* __restrict__ b2, float* __restrict__ out, int n_edges) {
  const int wave = threadIdx.x >> 6;
  const int lane = threadIdx.x & 63;
  const int w = blockIdx.x * 4 + wave;
  const int e0 = 2 * w;
  if (e0 >= n_edges) return;
  const bool has1 = (e0 + 1 < n_edges);
  const int j0 = lane * 8;
  const int u0 = edges[e0];
  const int v0 = edges[n_edges + e0];
  const int u1 = has1 ? edges[e0 + 1] : u0;
  const int v1 = has1 ? edges[n_edges + e0 + 1] : v0;
  short8 g0 = *(const short8*)(GH + (size_t)u0 * NCAT + j0);
  short8 h0 = *(const short8*)(GH + (size_t)v0 * NCAT + N1 + j0);
  short8 g1 = *(const short8*)(GH + (size_t)u1 * NCAT + j0);
  short8 h1 = *(const short8*)(GH + (size_t)v1 * NCAT + N1 + j0);
  float bv[8];
  {
    floatx4 t0 = *(const floatx4*)(b1 + j0);
    floatx4 t1 = *(const floatx4*)(b1 + j0 + 4);
#pragma unroll
    for (int j = 0; j < 4; ++j) { bv[j] = t0[j]; bv[4 + j] = t1[j]; }
  }
  float wv[16];
#pragma unroll
  for (int q = 0; q < 4; ++q) {
    floatx4 tt = *(const floatx4*)(W2 + (size_t)j0 * 2 + q * 4);
#pragma unroll
    for (int j = 0; j < 4; ++j) wv[q * 4 + j] = tt[j];
  }
  float s00 = 0.f, s01 = 0.f, s10 = 0.f, s11 = 0.f;
#pragma unroll
  for (int j = 0; j < 8; ++j) {
    float p0 = bf2f(g0[j]) + bf2f(h0[j]) + bv[j];
    p0 = p0 > 0.f ? p0 : 0.f;
    s00 += p0 * wv[2 * j];
    s01 += p0 * wv[2 * j + 1];
    float p1 = bf2f(g1[j]) + bf2f(h1[j]) + bv[j];
    p1 = p1 > 0.f ? p1 : 0.f;
    s10 += p1 * wv[2 * j];
    s11 += p1 * wv[2 * j + 1];
  }
#pragma unroll
  for (int off = 32; off > 0; off >>= 1) {
    s00 += __shfl_down(s00, off, 64);
    s01 += __shfl_down(s01, off, 64);
    s10 += __shfl_down(s10, off, 64);
    s11 += __shfl_down(s11, off, 64);
  }
  if (lane == 0) {
    out[2 * (size_t)e0]     = s00 + b2[0];
    out[2 * (size_t)e0 + 1] = s01 + b2[1];
    if (has1) {
      out[2 * (size_t)e0 + 2] = s10 + b2[0];
      out[2 * (size_t)e0 + 3] = s11 + b2[1];
    }
  }
}

// ---------------- tier-3 fallback: direct fp32 ----------------
__global__ __launch_bounds__(256) void slow_kernel(
    const float* __restrict__ feats, const int* __restrict__ edges,
    const float* __restrict__ W1, const float* __restrict__ b1,
    const float* __restrict__ W2, const float* __restrict__ b2,
    float* __restrict__ out, int n_edges) {
  const int wave = threadIdx.x >> 6;
  const int lane = threadIdx.x & 63;
  const int edge = blockIdx.x * 4 + wave;
  if (edge >= n_edges) return;
  const int u = edges[edge];
  const int v = edges[n_edges + edge];
  float f[4];
  f[0] = feats[(size_t)u * HID + lane];
  f[1] = feats[(size_t)u * HID + 64 + lane];
  f[2] = feats[(size_t)v * HID + lane];
  f[3] = feats[(size_t)v * HID + 64 + lane];
#pragma unroll
  for (int i = 0; i < 4; ++i) f[i] = f[i] > 0.f ? f[i] : 0.f;
  const int j0 = lane * 8;
  float acc[8];
#pragma unroll
  for (int j = 0; j < 8; ++j) acc[j] = 0.f;
#pragma unroll
  for (int seg = 0; seg < 4; ++seg) {
    float fs = f[seg];
    for (int k2 = 0; k2 < 64; ++k2) {
      float fk = __shfl(fs, k2, 64);
      const float* wr = W1 + (size_t)(seg * 64 + k2) * N1 + j0;
#pragma unroll
      for (int j = 0; j < 8; ++j) acc[j] += fk * wr[j];
    }
  }
  float s0 = 0.f, s1 = 0.f;
#pragma unroll
  for (int j = 0; j < 8; ++j) {
    float p = acc[j] + b1[j0 + j];
    p = p > 0.f ? p : 0.f;
    s0 += p * W2[(size_t)(j0 + j) * 2];
    s1 += p * W2[(size_t)(j0 + j) * 2 + 1];
  }
#pragma unroll
  for (int off = 32; off > 0; off >>= 1) {
    s0 += __shfl_down(s0, off, 64);
    s1 += __shfl_down(s1, off, 64);
  }
  if (lane == 0) {
    out[2 * (size_t)edge]     = s0 + b2[0];
    out[2 * (size_t)edge + 1] = s1 + b2[1];
  }
}

extern "C" void kernel_launch(void* const* d_in, const int* in_sizes, int n_in,
                              void* d_out, int out_size, void* d_ws, size_t ws_size,
                              hipStream_t stream) {
  const float* feats = (const float*)d_in[0];
  const int*   edges = (const int*)d_in[1];
  const float* W1    = (const float*)d_in[2];
  const float* b1    = (const float*)d_in[3];
  const float* W2    = (const float*)d_in[4];
  const float* b2    = (const float*)d_in[5];
  float* out = (float*)d_out;

  const int n_nodes = in_sizes[0] / HID;
  const int n_edges = in_sizes[1] / 2;

  const size_t bt_bytes   = (size_t)NCAT * HID * 2;       // 256 KiB
  const size_t misc_bytes = 4096;                         // W2T (2 KiB) + B1h (1 KiB)
  const size_t a_bytes    = (size_t)n_nodes * HID * 2;    // ~25.6 MB
  const size_t gh_bytes   = (size_t)n_nodes * NCAT * 2;   // ~204.8 MB

  if (ws_size >= bt_bytes + misc_bytes + a_bytes + gh_bytes) {
    f16* BT  = (f16*)d_ws;
    f16* W2T = (f16*)((char*)d_ws + bt_bytes);
    f16* B1h = (f16*)((char*)d_ws + bt_bytes + 2048);
    f16* A   = (f16*)((char*)d_ws + bt_bytes + misc_bytes);
    f16* GH  = (f16*)((char*)d_ws + bt_bytes + misc_bytes + a_bytes);
    const int total4 = n_nodes * HID / 4;
    const int prep_total = total4 + NCAT * HID + 1536;
    prep_all<<<(prep_total + 255) / 256, 256, 0, stream>>>(
        feats, W1, W2, b1, A, BT, W2T, B1h, total4);
    dim3 grid(NCAT / 64, (n_nodes + 511) / 512);
    gemm7_kernel<<<grid, 256, 0, stream>>>(A, BT, B1h, GH, n_nodes);
    const int ngrp = (n_edges + 1) / 2;          // edge pairs
    edge7_kernel<<<(ngrp + 15) / 16, 256, 0, stream>>>(GH, edges, W2T, b2, out, n_edges);
  } else if (ws_size >= bt_bytes + gh_bytes) {
    short* BT = (short*)d_ws;
    short* GH = (short*)((char*)d_ws + bt_bytes);
    conv_bt_bf<<<(NCAT * HID) / 256, 256, 0, stream>>>(W1, BT);
    dim3 grid((n_nodes + 63) / 64, NCAT / 128);
    gemm_bf<<<grid, 256, 0, stream>>>(feats, BT, GH, n_nodes);
    edge2_bf<<<((n_edges + 1) / 2 + 3) / 4, 256, 0, stream>>>(GH, edges, b1, W2, b2, out, n_edges);
  } else {
    slow_kernel<<<(n_edges + 3) / 4, 256, 0, stream>>>(feats, edges, W1, b1, W2, b2, out, n_edges);
  }
}